// Round 1
// baseline (49860.107 us; speedup 1.0000x reference)
//
#include <hip/hip_runtime.h>
#include <hip/hip_bf16.h>
#include <math.h>

// WaveNet forward on gfx950 — round 1: correct f32-FMA tiled GEMMs, bf16 storage.
// All heavy ops are 1x1-conv GEMMs; dilated FS=2 conv = two shifted 1x1 GEMMs.
// gc (speaker) conditioning folded into per-(layer,b,ch) bias (time-invariant).

#define TP 18432      // padded time stride (>= 18308, mult of 64)
#define SKS 16384     // skip buffer time stride
#define T_IN 18308
#define T_OUT 16262

typedef unsigned short u16;
typedef unsigned int u32;

__device__ __forceinline__ float bf2f(u16 h) { return __uint_as_float(((u32)h) << 16); }
__device__ __forceinline__ u16 f2bf(float f) {
  u32 u = __float_as_uint(f);
  return (u16)((u + 0x7fffu + ((u >> 16) & 1u)) >> 16);
}

__global__ void k_zero(float* p, long n) {
  for (long i = blockIdx.x * (long)blockDim.x + threadIdx.x; i < n; i += (long)gridDim.x * blockDim.x)
    p[i] = 0.0f;
}

__global__ void k_f32_to_bf16(const float* __restrict__ src, u16* __restrict__ dst, long n) {
  for (long i = blockIdx.x * (long)blockDim.x + threadIdx.x; i < n; i += (long)gridDim.x * blockDim.x)
    dst[i] = f2bf(src[i]);
}

// dst[k][m] = src[m][k]  (bf16 pack, transposed for coalesced per-k row reads)
__global__ void k_transpose_pack(const float* __restrict__ src, u16* __restrict__ dst, int M, int K) {
  long n = (long)M * K;
  for (long i = blockIdx.x * (long)blockDim.x + threadIdx.x; i < n; i += (long)gridDim.x * blockDim.x) {
    int m = (int)(i % M); long k = i / M;
    dst[k * M + m] = f2bf(src[(long)m * K + k]);
  }
}

// Pack fused gated-unit weights: dst[l][fg][c][896]
// k<384: tap0 of sig/gate conv; 384..768: tap1; 768..896: psig/pgate over lc channels.
__global__ void k_pack_fg(const float* __restrict__ sig_w, const float* __restrict__ gate_w,
                          const float* __restrict__ psig_w, const float* __restrict__ pgate_w,
                          u16* __restrict__ dst) {
  long total = 20L * 2 * 256 * 896;
  for (long i = blockIdx.x * (long)blockDim.x + threadIdx.x; i < total; i += (long)gridDim.x * blockDim.x) {
    int k = (int)(i % 896); long r = i / 896;
    int c = (int)(r % 256); r /= 256;
    int fg = (int)(r % 2); int l = (int)(r / 2);
    const float* w2 = fg ? gate_w : sig_w;    // [20][256][384][2]
    const float* p  = fg ? pgate_w : psig_w;  // [20][256][256][1]
    float v;
    if (k < 384)      v = w2[(((long)l * 256 + c) * 384 + k) * 2 + 0];
    else if (k < 768) v = w2[(((long)l * 256 + c) * 384 + (k - 384)) * 2 + 1];
    else              v = p[((long)l * 256 + c) * 256 + (k - 768)];
    dst[i] = f2bf(v);
  }
}

__global__ void k_gc(const float* __restrict__ emb_w, const float* __restrict__ emb_b,
                     const int* __restrict__ spk, float* __restrict__ gc) {
  int i = threadIdx.x + blockIdx.x * blockDim.x;
  if (i < 512) { int b = i / 128, g = i % 128; gc[b * 128 + g] = emb_w[g * 40 + spk[b]] + emb_b[g]; }
}

// cbias[l][fg][b][c] = (sig_b|gate_b)[l][c] + sum_g (psig|pgate)_w[l][c][128+g] * gc[b][g]
__global__ void k_cbias(const float* __restrict__ psig_w, const float* __restrict__ pgate_w,
                        const float* __restrict__ sig_b, const float* __restrict__ gate_b,
                        const float* __restrict__ gc, float* __restrict__ cbias) {
  int l = blockIdx.x; int fg = blockIdx.y >> 2; int b = blockIdx.y & 3; int c = threadIdx.x;
  const float* p = fg ? pgate_w : psig_w;
  const float* bb = fg ? gate_b : sig_b;
  float acc = bb[l * 256 + c];
  const float* prow = p + ((long)(l * 256 + c)) * 256 + 128;
  const float* g = gc + b * 128;
  for (int k = 0; k < 128; ++k) acc += prow[k] * g[k];
  cbias[((l * 2 + fg) * 4 + b) * 256 + c] = acc;
}

// jitter-gather + conv3 (VALID): out (B,128,62) f32, stride 64
__global__ void k_lc0(const float* __restrict__ lc_sparse, const int* __restrict__ jit,
                      const float* __restrict__ w, const float* __restrict__ bias, float* __restrict__ out) {
  int b = blockIdx.x; int co = threadIdx.x; // 128 threads
  __shared__ float xs[64][65];
  for (int i = threadIdx.x; i < 64 * 64; i += blockDim.x) {
    int ci = i >> 6, s = i & 63;
    xs[ci][s] = lc_sparse[((long)b * 64 + ci) * 64 + jit[b * 64 + s]];
  }
  __syncthreads();
  for (int t = 0; t < 62; ++t) {
    float acc = bias[co];
    for (int ci = 0; ci < 64; ++ci) {
      const float* wr = w + ((long)co * 64 + ci) * 3;
      acc += wr[0] * xs[ci][t] + wr[1] * xs[ci][t + 1] + wr[2] * xs[ci][t + 2];
    }
    out[((long)b * 128 + co) * 64 + t] = acc;
  }
}

// transposed conv: y[b][o][t] = bias[o] + sum_{i,valid k} w[i][o][K-1-k] * x[b][i][t/S + m]
// valid k = (S-1 - t%S) + m*S ; j = t/S + m
template<bool OUTBF>
__global__ void k_tconv(const float* __restrict__ xin, int Lin, int Sin,
                        void* __restrict__ yout, int Lout, int Sout,
                        const float* __restrict__ w, const float* __restrict__ bias, int S, int K) {
  int b = blockIdx.y;
  int t0 = blockIdx.x * 64;
  int o = threadIdx.x; // 128
  int nk = K / S;
  for (int tt = 0; tt < 64; ++tt) {
    int t = t0 + tt; if (t >= Lout) break;
    int kstart = S - 1 - (t % S);
    int jbase = t / S;
    float acc = bias[o];
    for (int i = 0; i < 128; ++i) {
      const float* xr = xin + ((long)b * 128 + i) * Sin;
      const float* wr = w + ((long)i * 128 + o) * K;
      #pragma unroll
      for (int m = 0; m < 7; ++m) {
        if (m >= nk) break;
        int j = jbase + m;
        if (j < Lin) acc += wr[K - 1 - (kstart + m * S)] * xr[j];
      }
    }
    if (OUTBF) ((u16*)yout)[((long)b * 128 + o) * Sout + t] = f2bf(acc);
    else ((float*)yout)[((long)b * 128 + o) * Sout + t] = acc;
  }
}

// Gated activation unit: dual GEMM (filt+gate), M=256, K=896, N=Lz per batch.
// z = tanh(filt+cbF) * sigmoid(gate+cbG), stored bf16.
__global__ __launch_bounds__(256) void k_gau(
    const u16* __restrict__ x, int Lx, const u16* __restrict__ lc,
    const u16* __restrict__ Wf, const u16* __restrict__ Wg,
    const float* __restrict__ cb, u16* __restrict__ z,
    int Lz, int d, int cl) {
  __shared__ __align__(16) float WsF[32][64];
  __shared__ __align__(16) float WsG[32][64];
  __shared__ __align__(16) float Xs[32][64];
  int b = blockIdx.z, bm0 = blockIdx.y * 64, t0 = blockIdx.x * 64;
  int tid = threadIdx.x, tn = tid & 15, tm = tid >> 4;
  float accF[4][4] = {}, accG[4][4] = {};
  int wl_m = tid >> 2, wl_k = (tid & 3) * 8;
  for (int kc = 0; kc < 28; ++kc) {
    int k0 = kc * 32;
    { // weight tiles (16B vector loads, pre-packed aligned)
      const u16* sf = Wf + (long)(bm0 + wl_m) * 896 + k0 + wl_k;
      const u16* sg = Wg + (long)(bm0 + wl_m) * 896 + k0 + wl_k;
      u16 tf[8], tg[8];
      *(uint4*)tf = *(const uint4*)sf;
      *(uint4*)tg = *(const uint4*)sg;
      #pragma unroll
      for (int j = 0; j < 8; ++j) { WsF[wl_k + j][wl_m] = bf2f(tf[j]); WsG[wl_k + j][wl_m] = bf2f(tg[j]); }
    }
    { // X tile: segment by K-chunk (tap0 / tap1 / lc-cond)
      const u16* xb; int rowbase, coloff, Lmax;
      if (kc < 12)      { xb = x + (long)b * 384 * TP; rowbase = k0;       coloff = t0;      Lmax = Lx; }
      else if (kc < 24) { xb = x + (long)b * 384 * TP; rowbase = k0 - 384; coloff = t0 + d;  Lmax = Lx; }
      else              { xb = lc + (long)b * 128 * TP; rowbase = k0 - 768; coloff = cl + t0; Lmax = T_IN; }
      #pragma unroll
      for (int r = 0; r < 8; ++r) {
        int kk = r * 4 + (tid >> 6), tt = tid & 63;
        int col = coloff + tt; if (col >= Lmax) col = Lmax - 1; // clamp; masked at store
        Xs[kk][tt] = bf2f(xb[(long)(rowbase + kk) * TP + col]);
      }
    }
    __syncthreads();
    #pragma unroll 8
    for (int kk = 0; kk < 32; ++kk) {
      float af[4], ag[4], bv[4];
      #pragma unroll
      for (int i = 0; i < 4; ++i) { af[i] = WsF[kk][tm * 4 + i]; ag[i] = WsG[kk][tm * 4 + i]; }
      #pragma unroll
      for (int j = 0; j < 4; ++j) bv[j] = Xs[kk][tn * 4 + j];
      #pragma unroll
      for (int i = 0; i < 4; ++i)
        #pragma unroll
        for (int j = 0; j < 4; ++j) {
          accF[i][j] = fmaf(af[i], bv[j], accF[i][j]);
          accG[i][j] = fmaf(ag[i], bv[j], accG[i][j]);
        }
    }
    __syncthreads();
  }
  #pragma unroll
  for (int i = 0; i < 4; ++i) {
    int ch = bm0 + tm * 4 + i;
    float bf = cb[b * 256 + ch];
    float bg = cb[1024 + b * 256 + ch];
    #pragma unroll
    for (int j = 0; j < 4; ++j) {
      int t = t0 + tn * 4 + j;
      if (t < Lz) {
        float f = accF[i][j] + bf;
        float g = accG[i][j] + bg;
        float zz = tanhf(f) * (1.0f / (1.0f + __expf(-g)));
        z[((long)b * 256 + ch) * TP + t] = f2bf(zz);
      }
    }
  }
}

// Generic single GEMM: MODE 0=base(+bias->bf16) 1=skip(+= f32) 2=res(+resid shifted ->bf16)
template<int MODE, bool XF32>
__global__ __launch_bounds__(256) void k_gemm(
    const void* __restrict__ xsrc, int xstride, int coloff, int Lmax,
    const u16* __restrict__ W, int K,
    const void* __restrict__ aux, void* __restrict__ out, int ostride, int N, int lw) {
  __shared__ __align__(16) float Ws[32][64];
  __shared__ __align__(16) float Xs[32][64];
  int b = blockIdx.z, bm0 = blockIdx.y * 64, t0 = blockIdx.x * 64;
  int tid = threadIdx.x, tn = tid & 15, tm = tid >> 4;
  float acc[4][4] = {};
  int wl_m = tid >> 2, wl_k = (tid & 3) * 8;
  int kchunks = K >> 5;
  for (int kc = 0; kc < kchunks; ++kc) {
    int k0 = kc * 32;
    {
      const u16* src = W + (long)(bm0 + wl_m) * K + k0 + wl_k;
      u16 tw[8];
      *(uint4*)tw = *(const uint4*)src;
      #pragma unroll
      for (int j = 0; j < 8; ++j) Ws[wl_k + j][wl_m] = bf2f(tw[j]);
    }
    #pragma unroll
    for (int r = 0; r < 8; ++r) {
      int kk = r * 4 + (tid >> 6), tt = tid & 63;
      int col = coloff + t0 + tt; if (col >= Lmax) col = Lmax - 1;
      float v;
      if (XF32) v = ((const float*)xsrc)[((long)b * K + k0 + kk) * (long)xstride + col];
      else      v = bf2f(((const u16*)xsrc)[((long)b * K + k0 + kk) * (long)xstride + col]);
      Xs[kk][tt] = v;
    }
    __syncthreads();
    #pragma unroll 8
    for (int kk = 0; kk < 32; ++kk) {
      float av[4], bv[4];
      #pragma unroll
      for (int i = 0; i < 4; ++i) av[i] = Ws[kk][tm * 4 + i];
      #pragma unroll
      for (int j = 0; j < 4; ++j) bv[j] = Xs[kk][tn * 4 + j];
      #pragma unroll
      for (int i = 0; i < 4; ++i)
        #pragma unroll
        for (int j = 0; j < 4; ++j) acc[i][j] = fmaf(av[i], bv[j], acc[i][j]);
    }
    __syncthreads();
  }
  int Mtot = gridDim.y * 64;
  #pragma unroll
  for (int i = 0; i < 4; ++i) {
    int ch = bm0 + tm * 4 + i;
    #pragma unroll
    for (int j = 0; j < 4; ++j) {
      int t = t0 + tn * 4 + j;
      if (t < N) {
        float v = acc[i][j];
        if (MODE == 0) {
          v += ((const float*)aux)[ch];
          ((u16*)out)[((long)b * Mtot + ch) * ostride + t] = f2bf(v);
        } else if (MODE == 1) {
          ((float*)out)[((long)b * Mtot + ch) * ostride + t] += v;
        } else {
          v += bf2f(((const u16*)aux)[((long)b * Mtot + ch) * TP + lw + t]);
          ((u16*)out)[((long)b * Mtot + ch) * ostride + t] = f2bf(v);
        }
      }
    }
  }
}

// fused relu -> post1(512x256) -> relu -> post2(256x512) -> log_softmax
__global__ __launch_bounds__(256) void k_post(
    const float* __restrict__ skip, const u16* __restrict__ p1T, const float* __restrict__ b1,
    const u16* __restrict__ p2T, const float* __restrict__ b2, float* __restrict__ out) {
  __shared__ float s_t[256][16];
  __shared__ float h1s[512][16];
  __shared__ float red[2][16][16];
  int b = blockIdx.y; int t0 = blockIdx.x * 16;
  int tid = threadIdx.x;
  for (int i = tid; i < 256 * 16; i += 256) {
    int c = i >> 4, j = i & 15;
    int t = t0 + j;
    float v = (t < T_OUT) ? skip[((long)b * 256 + c) * SKS + t] : 0.0f;
    s_t[c][j] = fmaxf(v, 0.0f);
  }
  __syncthreads();
  { // h1 rows tid, tid+256
    float acc0[16] = {}, acc1[16] = {};
    for (int k = 0; k < 256; ++k) {
      float w0 = bf2f(p1T[k * 512 + tid]);
      float w1 = bf2f(p1T[k * 512 + tid + 256]);
      #pragma unroll
      for (int j = 0; j < 16; ++j) { float s = s_t[k][j]; acc0[j] = fmaf(w0, s, acc0[j]); acc1[j] = fmaf(w1, s, acc1[j]); }
    }
    float bb0 = b1[tid], bb1 = b1[tid + 256];
    #pragma unroll
    for (int j = 0; j < 16; ++j) {
      h1s[tid][j] = fmaxf(acc0[j] + bb0, 0.f);
      h1s[tid + 256][j] = fmaxf(acc1[j] + bb1, 0.f);
    }
  }
  __syncthreads();
  float h2[16];
  { // h2 row tid
    float acc[16] = {};
    for (int k = 0; k < 512; ++k) {
      float w = bf2f(p2T[k * 256 + tid]);
      #pragma unroll
      for (int j = 0; j < 16; ++j) acc[j] = fmaf(w, h1s[k][j], acc[j]);
    }
    float bb = b2[tid];
    #pragma unroll
    for (int j = 0; j < 16; ++j) h2[j] = acc[j] + bb;
  }
  #pragma unroll
  for (int j = 0; j < 16; ++j) s_t[tid][j] = h2[j];
  __syncthreads();
  int j = tid & 15, grp = tid >> 4;
  float m = -1e30f;
  for (int c = grp * 16; c < grp * 16 + 16; ++c) m = fmaxf(m, s_t[c][j]);
  red[0][grp][j] = m;
  __syncthreads();
  if (tid < 16) {
    float mm = red[0][0][tid];
    for (int g = 1; g < 16; ++g) mm = fmaxf(mm, red[0][g][tid]);
    red[0][0][tid] = mm;
  }
  __syncthreads();
  float mj = red[0][0][j];
  float se = 0.f;
  for (int c = grp * 16; c < grp * 16 + 16; ++c) se += __expf(s_t[c][j] - mj);
  red[1][grp][j] = se;
  __syncthreads();
  if (tid < 16) {
    float ss = 0.f;
    for (int g = 0; g < 16; ++g) ss += red[1][g][tid];
    red[1][0][tid] = red[0][0][tid] + logf(ss);
  }
  __syncthreads();
  #pragma unroll
  for (int jj = 0; jj < 16; ++jj) {
    int t = t0 + jj;
    if (t < T_OUT) out[((long)b * 256 + tid) * T_OUT + t] = h2[jj] - red[1][0][jj];
  }
}

extern "C" void kernel_launch(void* const* d_in, const int* in_sizes, int n_in,
                              void* d_out, int out_size, void* d_ws, size_t ws_size,
                              hipStream_t stream) {
  const float* wav       = (const float*)d_in[0];
  const float* lc_sparse = (const float*)d_in[1];
  const float* lc_conv_w = (const float*)d_in[2];
  const float* lc_conv_b = (const float*)d_in[3];
  const float* ups_w[4]  = {(const float*)d_in[4], (const float*)d_in[6], (const float*)d_in[8], (const float*)d_in[10]};
  const float* ups_b[4]  = {(const float*)d_in[5], (const float*)d_in[7], (const float*)d_in[9], (const float*)d_in[11]};
  const float* emb_w     = (const float*)d_in[12];
  const float* emb_b     = (const float*)d_in[13];
  const float* base_w    = (const float*)d_in[14];
  const float* base_b    = (const float*)d_in[15];
  const float* sig_w     = (const float*)d_in[16];
  const float* sig_b     = (const float*)d_in[17];
  const float* gate_w    = (const float*)d_in[18];
  const float* gate_b    = (const float*)d_in[19];
  const float* psig_w    = (const float*)d_in[20];
  const float* pgate_w   = (const float*)d_in[21];
  const float* skp_w     = (const float*)d_in[22];
  const float* res_w     = (const float*)d_in[23];
  const float* post1_w   = (const float*)d_in[24];
  const float* post1_b   = (const float*)d_in[25];
  const float* post2_w   = (const float*)d_in[26];
  const float* post2_b   = (const float*)d_in[27];
  const int* spk         = (const int*)d_in[28];
  const int* jit         = (const int*)d_in[29];
  float* out = (float*)d_out;

  size_t off = 0;
  auto alloc = [&](size_t bytes) -> void* {
    off = (off + 255) & ~(size_t)255;
    void* p = (char*)d_ws + off;
    off += bytes;
    return p;
  };
  u16* wfg    = (u16*)alloc(20L * 2 * 256 * 896 * 2);
  u16* wskp   = (u16*)alloc(20L * 256 * 256 * 2);
  u16* wres   = (u16*)alloc(20L * 384 * 256 * 2);
  u16* wbase  = (u16*)alloc(384L * 256 * 2);
  u16* wp1T   = (u16*)alloc(256L * 512 * 2);
  u16* wp2T   = (u16*)alloc(512L * 256 * 2);
  float* cbias = (float*)alloc(20L * 2 * 4 * 256 * 4);
  float* gc    = (float*)alloc(4L * 128 * 4);
  float* lcs0  = (float*)alloc(4L * 128 * 64 * 4);
  float* lcs1  = (float*)alloc(4L * 128 * 290 * 4);
  float* lcs2  = (float*)alloc(4L * 128 * 1148 * 4);
  float* lcs3  = (float*)alloc(4L * 128 * 4580 * 4);
  u16* lcbf    = (u16*)alloc(4L * 128 * TP * 2);
  u16* xA      = (u16*)alloc(4L * 384 * TP * 2);
  u16* xB      = (u16*)alloc(4L * 384 * TP * 2);
  u16* zbuf    = (u16*)alloc(4L * 256 * TP * 2);
  float* skip  = (float*)alloc(4L * 256 * SKS * 4);
  (void)ws_size; (void)in_sizes; (void)n_in; (void)out_size; // ~275 MB total

  // weight packs (re-run every call; deterministic)
  k_pack_fg<<<2048, 256, 0, stream>>>(sig_w, gate_w, psig_w, pgate_w, wfg);
  k_f32_to_bf16<<<1024, 256, 0, stream>>>(skp_w, wskp, 20L * 256 * 256);
  k_f32_to_bf16<<<1024, 256, 0, stream>>>(res_w, wres, 20L * 384 * 256);
  k_f32_to_bf16<<<256, 256, 0, stream>>>(base_w, wbase, 384L * 256);
  k_transpose_pack<<<256, 256, 0, stream>>>(post1_w, wp1T, 512, 256);
  k_transpose_pack<<<256, 256, 0, stream>>>(post2_w, wp2T, 256, 512);
  k_gc<<<1, 512, 0, stream>>>(emb_w, emb_b, spk, gc);
  k_cbias<<<dim3(20, 8), 256, 0, stream>>>(psig_w, pgate_w, sig_b, gate_b, gc, cbias);

  // local-conditioning chain
  k_lc0<<<4, 128, 0, stream>>>(lc_sparse, jit, lc_conv_w, lc_conv_b, lcs0);
  k_tconv<false><<<dim3(5, 4), 128, 0, stream>>>(lcs0, 62, 64, lcs1, 290, 290, ups_w[0], ups_b[0], 5, 25);
  k_tconv<false><<<dim3(18, 4), 128, 0, stream>>>(lcs1, 290, 290, lcs2, 1148, 1148, ups_w[1], ups_b[1], 4, 16);
  k_tconv<false><<<dim3(72, 4), 128, 0, stream>>>(lcs2, 1148, 1148, lcs3, 4580, 4580, ups_w[2], ups_b[2], 4, 16);
  k_tconv<true><<<dim3(287, 4), 128, 0, stream>>>(lcs3, 4580, 4580, lcbf, T_IN, TP, ups_w[3], ups_b[3], 4, 16);

  // base 1x1 conv: x0 = base_w @ wav + base_b
  k_gemm<0, true><<<dim3(287, 6, 4), 256, 0, stream>>>(wav, T_IN, 0, T_IN, wbase, 256, base_b, xA, TP, T_IN, 0);

  k_zero<<<2048, 256, 0, stream>>>(skip, 4L * 256 * SKS);

  static const int DILS[20] = {1, 2, 4, 8, 16, 32, 64, 128, 256, 512,
                               1, 2, 4, 8, 16, 32, 64, 128, 256, 512};
  int cum = 0;
  u16* xc = xA; u16* xn = xB;
  for (int l = 0; l < 20; ++l) {
    int dd = DILS[l], lw = dd, cl = cum + lw;
    int Lx = T_IN - cum, Lz = T_IN - cl;
    int sl = 2046 - cl;
    const u16* Wf = wfg + (long)l * 2 * 256 * 896;
    const u16* Wg = Wf + 256 * 896;
    k_gau<<<dim3((Lz + 63) / 64, 4, 4), 256, 0, stream>>>(
        xc, Lx, lcbf, Wf, Wg, cbias + (long)l * 2048, zbuf, Lz, dd, cl);
    k_gemm<1, false><<<dim3((T_OUT + 63) / 64, 4, 4), 256, 0, stream>>>(
        zbuf, TP, sl, Lz, wskp + (long)l * 256 * 256, 256, nullptr, skip, SKS, T_OUT, 0);
    k_gemm<2, false><<<dim3((Lz + 63) / 64, 6, 4), 256, 0, stream>>>(
        zbuf, TP, 0, Lz, wres + (long)l * 384 * 256, 256, xc, xn, TP, Lz, lw);
    cum = cl;
    u16* t = xc; xc = xn; xn = t;
  }

  k_post<<<dim3((T_OUT + 15) / 16, 4), 256, 0, stream>>>(skip, wp1T, post1_b, wp2T, post2_b, out);
}

// Round 2
// 7607.576 us; speedup vs baseline: 6.5540x; 6.5540x over previous
//
#include <hip/hip_runtime.h>
#include <hip/hip_bf16.h>
#include <math.h>

// WaveNet forward on gfx950 — round 2: MFMA bf16 GEMMs (t-major activations,
// fragment-packed weights), tconv as per-phase tiled GEMM.

#define T_IN 18308
#define T_OUT 16262

typedef unsigned short u16;
typedef unsigned int u32;
typedef __attribute__((ext_vector_type(8))) short short8_t;
typedef __attribute__((ext_vector_type(4))) float f32x4;

__device__ __forceinline__ float bf2f(u16 h) { return __uint_as_float(((u32)h) << 16); }
__device__ __forceinline__ u16 f2bf(float f) {
  u32 u = __float_as_uint(f);
  return (u16)((u + 0x7fffu + ((u >> 16) & 1u)) >> 16);
}

__global__ void k_zero(float* p, long n) {
  for (long i = blockIdx.x * (long)blockDim.x + threadIdx.x; i < n; i += (long)gridDim.x * blockDim.x)
    p[i] = 0.0f;
}

__global__ void k_f32_to_bf16(const float* __restrict__ src, u16* __restrict__ dst, long n) {
  for (long i = blockIdx.x * (long)blockDim.x + threadIdx.x; i < n; i += (long)gridDim.x * blockDim.x)
    dst[i] = f2bf(src[i]);
}

// dst[k][m] = src[m][k]
__global__ void k_transpose_pack(const float* __restrict__ src, u16* __restrict__ dst, int M, int K) {
  long n = (long)M * K;
  for (long i = blockIdx.x * (long)blockDim.x + threadIdx.x; i < n; i += (long)gridDim.x * blockDim.x) {
    int m = (int)(i % M); long k = i / M;
    dst[k * M + m] = f2bf(src[(long)m * K + k]);
  }
}

// ---- MFMA fragment packing ----
// Frag layout per (mt,ks): dst[(mt*nks+ks)*512 + lane*8 + j] = W[mt*16+(lane&15)][ks*32+(lane>>4)*8+j]
__global__ void k_pack_frag(const float* __restrict__ src, u16* __restrict__ dst,
                            int M, int K, int L, long src_lstride) {
  int nks = K >> 5;
  long per = (long)M * K;
  long total = per * L;
  for (long idx = blockIdx.x * (long)blockDim.x + threadIdx.x; idx < total; idx += (long)gridDim.x * blockDim.x) {
    int l = (int)(idx / per); long r = idx - (long)l * per;
    int j = (int)(r & 7); int lane = (int)((r >> 3) & 63); int fid = (int)(r >> 9);
    int ks = fid % nks; int mt = fid / nks;
    int row = mt * 16 + (lane & 15);
    int col = ks * 32 + ((lane >> 4) << 3) + j;
    dst[idx] = f2bf(src[l * src_lstride + (long)row * K + col]);
  }
}

// GAU fused weights: logical W[l][256][896]: k<384 tap0, k<768 tap1, else psig(lc chans 0..127)
__global__ void k_pack_frag_gau(const float* __restrict__ sig_w, const float* __restrict__ gate_w,
                                const float* __restrict__ psig_w, const float* __restrict__ pgate_w,
                                u16* __restrict__ dstF, u16* __restrict__ dstG) {
  const long per = 229376; // 16mt * 28ks * 512
  long total = per * 20;
  for (long idx = blockIdx.x * (long)blockDim.x + threadIdx.x; idx < total; idx += (long)gridDim.x * blockDim.x) {
    int l = (int)(idx / per); long r = idx - (long)l * per;
    int j = (int)(r & 7); int lane = (int)((r >> 3) & 63); int fid = (int)(r >> 9);
    int ks = fid % 28; int mt = fid / 28;
    int row = mt * 16 + (lane & 15);
    int k = ks * 32 + ((lane >> 4) << 3) + j;
    float vF, vG;
    if (k < 384) {
      vF = sig_w[(((long)l * 256 + row) * 384 + k) * 2 + 0];
      vG = gate_w[(((long)l * 256 + row) * 384 + k) * 2 + 0];
    } else if (k < 768) {
      vF = sig_w[(((long)l * 256 + row) * 384 + (k - 384)) * 2 + 1];
      vG = gate_w[(((long)l * 256 + row) * 384 + (k - 384)) * 2 + 1];
    } else {
      vF = psig_w[((long)l * 256 + row) * 256 + (k - 768)];
      vG = pgate_w[((long)l * 256 + row) * 256 + (k - 768)];
    }
    dstF[idx] = f2bf(vF);
    dstG[idx] = f2bf(vG);
  }
}

// tconv per-phase weight pack: dst[p][i*nk+m][o] = w[i][o][K-1-(S-1-p)-m*S]
__global__ void k_pack_tconv(const float* __restrict__ w, float* __restrict__ dst,
                             int S, int K, int nk) {
  int Ktot = 128 * nk;
  long total = (long)S * Ktot * 128;
  for (long idx = blockIdx.x * (long)blockDim.x + threadIdx.x; idx < total; idx += (long)gridDim.x * blockDim.x) {
    int o = (int)(idx & 127);
    long tmp = idx >> 7;
    int k = (int)(tmp % Ktot);
    int p = (int)(tmp / Ktot);
    int i = k / nk, m = k % nk;
    dst[idx] = w[((long)i * 128 + o) * K + (K - 1 - (S - 1 - p) - m * S)];
  }
}

__global__ void k_gc(const float* __restrict__ emb_w, const float* __restrict__ emb_b,
                     const int* __restrict__ spk, float* __restrict__ gc) {
  int i = threadIdx.x + blockIdx.x * blockDim.x;
  if (i < 512) { int b = i / 128, g = i % 128; gc[b * 128 + g] = emb_w[g * 40 + spk[b]] + emb_b[g]; }
}

__global__ void k_cbias(const float* __restrict__ psig_w, const float* __restrict__ pgate_w,
                        const float* __restrict__ sig_b, const float* __restrict__ gate_b,
                        const float* __restrict__ gc, float* __restrict__ cbias) {
  int l = blockIdx.x; int fg = blockIdx.y >> 2; int b = blockIdx.y & 3; int c = threadIdx.x;
  const float* p = fg ? pgate_w : psig_w;
  const float* bb = fg ? gate_b : sig_b;
  float acc = bb[l * 256 + c];
  const float* prow = p + ((long)(l * 256 + c)) * 256 + 128;
  const float* g = gc + b * 128;
  for (int k = 0; k < 128; ++k) acc += prow[k] * g[k];
  cbias[((l * 2 + fg) * 4 + b) * 256 + c] = acc;
}

// jitter-gather + conv3 (VALID): out (B,128,62) f32 ch-major, stride 64
__global__ void k_lc0(const float* __restrict__ lc_sparse, const int* __restrict__ jit,
                      const float* __restrict__ w, const float* __restrict__ bias, float* __restrict__ out) {
  int b = blockIdx.x; int co = threadIdx.x;
  __shared__ float xs[64][65];
  for (int i = threadIdx.x; i < 64 * 64; i += blockDim.x) {
    int ci = i >> 6, s = i & 63;
    xs[ci][s] = lc_sparse[((long)b * 64 + ci) * 64 + jit[b * 64 + s]];
  }
  __syncthreads();
  for (int t = 0; t < 62; ++t) {
    float acc = bias[co];
    for (int ci = 0; ci < 64; ++ci) {
      const float* wr = w + ((long)co * 64 + ci) * 3;
      acc += wr[0] * xs[ci][t] + wr[1] * xs[ci][t + 1] + wr[2] * xs[ci][t + 2];
    }
    out[((long)b * 128 + co) * 64 + t] = acc;
  }
}

// Transposed conv as per-phase tiled GEMM. y[jS+p][o] = bias[o] + sum_k wp[p][k][o]*x[i(k)][j+m(k)]
// OUTBF=false: out f32 ch-major [b][128][ostride]; true: out bf16 t-major [b][Lout][128]
template<int NK, bool OUTBF>
__global__ __launch_bounds__(256) void k_tconvg(
    const float* __restrict__ xin, int Lin, int xstride,
    void* __restrict__ yout, int Lout, int ostride,
    const float* __restrict__ wp, const float* __restrict__ bias, int S) {
  const int Ktot = 128 * NK;
  __shared__ __align__(16) float Ws[32][64];
  __shared__ __align__(16) float Xs[32][64];
  int b = blockIdx.z;
  int p = blockIdx.y >> 1, bm0 = (blockIdx.y & 1) * 64;
  int j0 = blockIdx.x * 64;
  int tid = threadIdx.x, tn = tid & 15, tm = tid >> 4;
  float acc[4][4] = {};
  int kchunks = Ktot / 32;
  for (int kc = 0; kc < kchunks; ++kc) {
    int k0 = kc * 32;
    { // weights: 8 f32 per thread
      int kk = tid >> 3, m8 = (tid & 7) * 8;
      const float* src = wp + ((long)p * Ktot + k0 + kk) * 128 + bm0 + m8;
      float4 f1 = *(const float4*)src;
      float4 f2 = *(const float4*)(src + 4);
      Ws[kk][m8 + 0] = f1.x; Ws[kk][m8 + 1] = f1.y; Ws[kk][m8 + 2] = f1.z; Ws[kk][m8 + 3] = f1.w;
      Ws[kk][m8 + 4] = f2.x; Ws[kk][m8 + 5] = f2.y; Ws[kk][m8 + 6] = f2.z; Ws[kk][m8 + 7] = f2.w;
    }
    #pragma unroll
    for (int rr = 0; rr < 8; ++rr) {
      int kk = rr * 4 + (tid >> 6), tt = tid & 63;
      int k = k0 + kk;
      int i = k / NK, m = k % NK;
      int j = j0 + tt;
      Xs[kk][tt] = (j + m < Lin) ? xin[((long)(b * 128 + i)) * xstride + j + m] : 0.0f;
    }
    __syncthreads();
    #pragma unroll 8
    for (int kk = 0; kk < 32; ++kk) {
      float av[4], bv[4];
      #pragma unroll
      for (int i = 0; i < 4; ++i) av[i] = Ws[kk][tm * 4 + i];
      #pragma unroll
      for (int j = 0; j < 4; ++j) bv[j] = Xs[kk][tn * 4 + j];
      #pragma unroll
      for (int i = 0; i < 4; ++i)
        #pragma unroll
        for (int j = 0; j < 4; ++j) acc[i][j] = fmaf(av[i], bv[j], acc[i][j]);
    }
    __syncthreads();
  }
  #pragma unroll
  for (int jj = 0; jj < 4; ++jj) {
    int j = j0 + tn * 4 + jj;
    int t = j * S + p;
    if (t >= Lout) continue;
    if (OUTBF) {
      int o0 = bm0 + tm * 4;
      ushort4 o;
      o.x = f2bf(acc[0][jj] + bias[o0 + 0]);
      o.y = f2bf(acc[1][jj] + bias[o0 + 1]);
      o.z = f2bf(acc[2][jj] + bias[o0 + 2]);
      o.w = f2bf(acc[3][jj] + bias[o0 + 3]);
      *(ushort4*)((u16*)yout + ((long)b * Lout + t) * 128 + o0) = o;
    } else {
      #pragma unroll
      for (int i = 0; i < 4; ++i) {
        int o = bm0 + tm * 4 + i;
        ((float*)yout)[((long)b * 128 + o) * ostride + t] = acc[i][jj] + bias[o];
      }
    }
  }
}

// base conv: f32 X ch-major (wav), bf16 W row-major [384][256], out bf16 t-major [b][T_IN][384]
__global__ __launch_bounds__(256) void k_base(
    const float* __restrict__ wav, const u16* __restrict__ W,
    const float* __restrict__ bias, u16* __restrict__ out) {
  __shared__ __align__(16) float Ws[32][64];
  __shared__ __align__(16) float Xs[32][64];
  int b = blockIdx.z, bm0 = blockIdx.y * 64, t0 = blockIdx.x * 64;
  int tid = threadIdx.x, tn = tid & 15, tm = tid >> 4;
  float acc[4][4] = {};
  int wl_m = tid >> 2, wl_k = (tid & 3) * 8;
  for (int kc = 0; kc < 8; ++kc) {
    int k0 = kc * 32;
    {
      const u16* src = W + (long)(bm0 + wl_m) * 256 + k0 + wl_k;
      u16 tw[8];
      *(uint4*)tw = *(const uint4*)src;
      #pragma unroll
      for (int j = 0; j < 8; ++j) Ws[wl_k + j][wl_m] = bf2f(tw[j]);
    }
    #pragma unroll
    for (int r = 0; r < 8; ++r) {
      int kk = r * 4 + (tid >> 6), tt = tid & 63;
      int col = t0 + tt; if (col >= T_IN) col = T_IN - 1;
      Xs[kk][tt] = wav[((long)b * 256 + k0 + kk) * T_IN + col];
    }
    __syncthreads();
    #pragma unroll 8
    for (int kk = 0; kk < 32; ++kk) {
      float av[4], bv[4];
      #pragma unroll
      for (int i = 0; i < 4; ++i) av[i] = Ws[kk][tm * 4 + i];
      #pragma unroll
      for (int j = 0; j < 4; ++j) bv[j] = Xs[kk][tn * 4 + j];
      #pragma unroll
      for (int i = 0; i < 4; ++i)
        #pragma unroll
        for (int j = 0; j < 4; ++j) acc[i][j] = fmaf(av[i], bv[j], acc[i][j]);
    }
    __syncthreads();
  }
  #pragma unroll
  for (int jj = 0; jj < 4; ++jj) {
    int t = t0 + tn * 4 + jj;
    if (t >= T_IN) continue;
    int ch0 = bm0 + tm * 4;
    ushort4 o;
    o.x = f2bf(acc[0][jj] + bias[ch0 + 0]);
    o.y = f2bf(acc[1][jj] + bias[ch0 + 1]);
    o.z = f2bf(acc[2][jj] + bias[ch0 + 2]);
    o.w = f2bf(acc[3][jj] + bias[ch0 + 3]);
    *(ushort4*)(out + ((long)b * T_IN + t) * 384 + ch0) = o;
  }
}

// ---- MFMA GEMMs ----
// Per block: 4 waves, 64ch x 256t; per wave 64ch x 64t (4 M-frags x 4 N-frags).
// A (weights) fragment-packed; B from t-major bf16; D: col=lane&15, row=4*(lane>>4)+reg.

// GAU: dual F/G accumulators, segmented K (tap0/tap1/cond), fused activation -> z bf16 t-major
__global__ __launch_bounds__(256) void k_gaum(
    const u16* __restrict__ Xc, const u16* __restrict__ Lc,
    const u16* __restrict__ WpF, const u16* __restrict__ WpG,
    const float* __restrict__ cb, u16* __restrict__ Z,
    int Lz, int Lx, int d, int cl) {
  int lane = threadIdx.x & 63, wave = threadIdx.x >> 6;
  int b = blockIdx.z, chb = blockIdx.y << 6;
  int tbase = (blockIdx.x << 8) + (wave << 6);
  int lrow = lane & 15, lk = (lane >> 4) << 3;
  int mt0 = chb >> 4;
  const long bxs = (long)T_IN * 384, blcs = (long)T_IN * 128, bzs = (long)T_IN * 256;
  f32x4 zed = {0.f, 0.f, 0.f, 0.f};
  f32x4 accF[4][4], accG[4][4];
  #pragma unroll
  for (int m = 0; m < 4; ++m)
    #pragma unroll
    for (int n = 0; n < 4; ++n) { accF[m][n] = zed; accG[m][n] = zed; }
  const u16* xb = Xc + (long)b * bxs;
  const u16* lb = Lc + (long)b * blcs;
  for (int ks = 0; ks < 28; ++ks) {
    short8_t af[4], ag[4];
    #pragma unroll
    for (int m = 0; m < 4; ++m) {
      long fo = ((long)((mt0 + m) * 28 + ks) << 9) + (lane << 3);
      af[m] = *(const short8_t*)(WpF + fo);
      ag[m] = *(const short8_t*)(WpG + fo);
    }
    const u16* src; int koff, rowadd, ldB, clampv;
    if (ks < 12)      { src = xb; koff = ks * 32;        rowadd = 0;  ldB = 384; clampv = Lx - 1; }
    else if (ks < 24) { src = xb; koff = ks * 32 - 384;  rowadd = d;  ldB = 384; clampv = Lx - 1; }
    else              { src = lb; koff = ks * 32 - 768;  rowadd = cl; ldB = 128; clampv = T_IN - 1; }
    #pragma unroll
    for (int n = 0; n < 4; ++n) {
      int row = tbase + (n << 4) + lrow + rowadd;
      row = min(row, clampv);
      short8_t bv = *(const short8_t*)(src + (long)row * ldB + koff + lk);
      #pragma unroll
      for (int m = 0; m < 4; ++m) {
        accF[m][n] = __builtin_amdgcn_mfma_f32_16x16x32_bf16(af[m], bv, accF[m][n], 0, 0, 0);
        accG[m][n] = __builtin_amdgcn_mfma_f32_16x16x32_bf16(ag[m], bv, accG[m][n], 0, 0, 0);
      }
    }
  }
  const float* cbF = cb + b * 256;
  const float* cbG = cb + 1024 + b * 256;
  #pragma unroll
  for (int n = 0; n < 4; ++n) {
    int t = tbase + (n << 4) + lrow;
    if (t >= Lz) continue;
    #pragma unroll
    for (int m = 0; m < 4; ++m) {
      int ch0 = chb + (m << 4) + ((lane >> 4) << 2);
      f32x4 bf = *(const f32x4*)(cbF + ch0);
      f32x4 bg = *(const f32x4*)(cbG + ch0);
      ushort4 o;
      #pragma unroll
      for (int r = 0; r < 4; ++r) {
        float f = accF[m][n][r] + bf[r];
        float g = accG[m][n][r] + bg[r];
        f = fminf(fmaxf(f, -15.f), 15.f);
        float e2 = __expf(2.f * f);
        float th = 1.f - 2.f * __builtin_amdgcn_rcpf(e2 + 1.f);
        float sg = __builtin_amdgcn_rcpf(1.f + __expf(-g));
        u16 zz = f2bf(th * sg);
        if (r == 0) o.x = zz; else if (r == 1) o.y = zz; else if (r == 2) o.z = zz; else o.w = zz;
      }
      *(ushort4*)(Z + (long)b * bzs + (long)t * 256 + ch0) = o;
    }
  }
}

// MODE 1: skip f32 += acc (in-place, t-major). MODE 2: out bf16 = acc + residual(aux row t+auxrowoff)
template<int MODE>
__global__ __launch_bounds__(256) void k_mgemm(
    const u16* __restrict__ X, long bxs, int ldx, int rowoff, int rowclamp,
    const u16* __restrict__ Wp, int nks,
    const u16* __restrict__ aux, long bas, int auxrowoff,
    void* __restrict__ outp, long bos, int ldo, int Nvalid) {
  int lane = threadIdx.x & 63, wave = threadIdx.x >> 6;
  int b = blockIdx.z, chb = blockIdx.y << 6;
  int tbase = (blockIdx.x << 8) + (wave << 6);
  int lrow = lane & 15, lk = (lane >> 4) << 3;
  int mt0 = chb >> 4;
  f32x4 zed = {0.f, 0.f, 0.f, 0.f};
  f32x4 acc[4][4];
  #pragma unroll
  for (int m = 0; m < 4; ++m)
    #pragma unroll
    for (int n = 0; n < 4; ++n) acc[m][n] = zed;
  const u16* xb = X + (long)b * bxs;
  for (int ks = 0; ks < nks; ++ks) {
    short8_t a[4];
    #pragma unroll
    for (int m = 0; m < 4; ++m)
      a[m] = *(const short8_t*)(Wp + ((long)((mt0 + m) * nks + ks) << 9) + (lane << 3));
    #pragma unroll
    for (int n = 0; n < 4; ++n) {
      int row = rowoff + tbase + (n << 4) + lrow;
      row = min(row, rowclamp);
      short8_t bv = *(const short8_t*)(xb + (long)row * ldx + (ks << 5) + lk);
      #pragma unroll
      for (int m = 0; m < 4; ++m)
        acc[m][n] = __builtin_amdgcn_mfma_f32_16x16x32_bf16(a[m], bv, acc[m][n], 0, 0, 0);
    }
  }
  #pragma unroll
  for (int n = 0; n < 4; ++n) {
    int t = tbase + (n << 4) + lrow;
    if (t >= Nvalid) continue;
    #pragma unroll
    for (int m = 0; m < 4; ++m) {
      int ch0 = chb + (m << 4) + ((lane >> 4) << 2);
      if (MODE == 1) {
        float* p = (float*)outp + (long)b * bos + (long)t * ldo + ch0;
        f32x4 v = *(f32x4*)p;
        v += acc[m][n];
        *(f32x4*)p = v;
      } else {
        const u16* rp = aux + (long)b * bas + (long)(t + auxrowoff) * ldo + ch0;
        ushort4 rv = *(const ushort4*)rp;
        ushort4 o;
        o.x = f2bf(acc[m][n][0] + bf2f(rv.x));
        o.y = f2bf(acc[m][n][1] + bf2f(rv.y));
        o.z = f2bf(acc[m][n][2] + bf2f(rv.z));
        o.w = f2bf(acc[m][n][3] + bf2f(rv.w));
        *(ushort4*)((u16*)outp + (long)b * bos + (long)t * ldo + ch0) = o;
      }
    }
  }
}

// fused relu -> post1 -> relu -> post2 -> log_softmax ; skip is t-major f32 [b][T_OUT][256]
__global__ __launch_bounds__(256) void k_post(
    const float* __restrict__ skip, const u16* __restrict__ p1T, const float* __restrict__ b1,
    const u16* __restrict__ p2T, const float* __restrict__ b2, float* __restrict__ out) {
  __shared__ float s_t[256][17];
  __shared__ float h1s[512][17];
  __shared__ float red[2][16][16];
  int b = blockIdx.y; int t0 = blockIdx.x * 16;
  int tid = threadIdx.x;
  const float* skipb = skip + (long)b * T_OUT * 256;
  for (int i = tid; i < 4096; i += 256) {
    int c = i & 255, j = i >> 8;
    int t = t0 + j;
    float v = (t < T_OUT) ? skipb[(long)t * 256 + c] : 0.0f;
    s_t[c][j] = fmaxf(v, 0.0f);
  }
  __syncthreads();
  {
    float acc0[16] = {}, acc1[16] = {};
    for (int k = 0; k < 256; ++k) {
      float w0 = bf2f(p1T[k * 512 + tid]);
      float w1 = bf2f(p1T[k * 512 + tid + 256]);
      #pragma unroll
      for (int j = 0; j < 16; ++j) { float s = s_t[k][j]; acc0[j] = fmaf(w0, s, acc0[j]); acc1[j] = fmaf(w1, s, acc1[j]); }
    }
    float bb0 = b1[tid], bb1 = b1[tid + 256];
    #pragma unroll
    for (int j = 0; j < 16; ++j) {
      h1s[tid][j] = fmaxf(acc0[j] + bb0, 0.f);
      h1s[tid + 256][j] = fmaxf(acc1[j] + bb1, 0.f);
    }
  }
  __syncthreads();
  float h2[16];
  {
    float acc[16] = {};
    for (int k = 0; k < 512; ++k) {
      float w = bf2f(p2T[k * 256 + tid]);
      #pragma unroll
      for (int j = 0; j < 16; ++j) acc[j] = fmaf(w, h1s[k][j], acc[j]);
    }
    float bb = b2[tid];
    #pragma unroll
    for (int j = 0; j < 16; ++j) h2[j] = acc[j] + bb;
  }
  #pragma unroll
  for (int j = 0; j < 16; ++j) s_t[tid][j] = h2[j];
  __syncthreads();
  int j = tid & 15, grp = tid >> 4;
  float m = -1e30f;
  for (int c = grp * 16; c < grp * 16 + 16; ++c) m = fmaxf(m, s_t[c][j]);
  red[0][grp][j] = m;
  __syncthreads();
  if (tid < 16) {
    float mm = red[0][0][tid];
    for (int g = 1; g < 16; ++g) mm = fmaxf(mm, red[0][g][tid]);
    red[0][0][tid] = mm;
  }
  __syncthreads();
  float mj = red[0][0][j];
  float se = 0.f;
  for (int c = grp * 16; c < grp * 16 + 16; ++c) se += __expf(s_t[c][j] - mj);
  red[1][grp][j] = se;
  __syncthreads();
  if (tid < 16) {
    float ss = 0.f;
    for (int g = 0; g < 16; ++g) ss += red[1][g][tid];
    red[1][0][tid] = red[0][0][tid] + logf(ss);
  }
  __syncthreads();
  #pragma unroll
  for (int jj = 0; jj < 16; ++jj) {
    int t = t0 + jj;
    if (t < T_OUT) out[((long)b * 256 + tid) * T_OUT + t] = h2[jj] - red[1][0][jj];
  }
}

extern "C" void kernel_launch(void* const* d_in, const int* in_sizes, int n_in,
                              void* d_out, int out_size, void* d_ws, size_t ws_size,
                              hipStream_t stream) {
  const float* wav       = (const float*)d_in[0];
  const float* lc_sparse = (const float*)d_in[1];
  const float* lc_conv_w = (const float*)d_in[2];
  const float* lc_conv_b = (const float*)d_in[3];
  const float* ups_w[4]  = {(const float*)d_in[4], (const float*)d_in[6], (const float*)d_in[8], (const float*)d_in[10]};
  const float* ups_b[4]  = {(const float*)d_in[5], (const float*)d_in[7], (const float*)d_in[9], (const float*)d_in[11]};
  const float* emb_w     = (const float*)d_in[12];
  const float* emb_b     = (const float*)d_in[13];
  const float* base_w    = (const float*)d_in[14];
  const float* base_b    = (const float*)d_in[15];
  const float* sig_w     = (const float*)d_in[16];
  const float* sig_b     = (const float*)d_in[17];
  const float* gate_w    = (const float*)d_in[18];
  const float* gate_b    = (const float*)d_in[19];
  const float* psig_w    = (const float*)d_in[20];
  const float* pgate_w   = (const float*)d_in[21];
  const float* skp_w     = (const float*)d_in[22];
  const float* res_w     = (const float*)d_in[23];
  const float* post1_w   = (const float*)d_in[24];
  const float* post1_b   = (const float*)d_in[25];
  const float* post2_w   = (const float*)d_in[26];
  const float* post2_b   = (const float*)d_in[27];
  const int* spk         = (const int*)d_in[28];
  const int* jit         = (const int*)d_in[29];
  float* out = (float*)d_out;

  size_t off = 0;
  auto alloc = [&](size_t bytes) -> void* {
    off = (off + 255) & ~(size_t)255;
    void* p = (char*)d_ws + off;
    off += bytes;
    return p;
  };
  u16* wfgF   = (u16*)alloc(20L * 229376 * 2);
  u16* wfgG   = (u16*)alloc(20L * 229376 * 2);
  u16* wskpF  = (u16*)alloc(20L * 256 * 256 * 2);
  u16* wresF  = (u16*)alloc(20L * 384 * 256 * 2);
  u16* wbase  = (u16*)alloc(384L * 256 * 2);
  u16* wp1T   = (u16*)alloc(256L * 512 * 2);
  u16* wp2T   = (u16*)alloc(512L * 256 * 2);
  float* wtc1 = (float*)alloc(5L * 640 * 128 * 4);
  float* wtc2 = (float*)alloc(4L * 512 * 128 * 4);
  float* wtc3 = (float*)alloc(4L * 512 * 128 * 4);
  float* wtc4 = (float*)alloc(4L * 512 * 128 * 4);
  float* cbias = (float*)alloc(20L * 2 * 4 * 256 * 4);
  float* gc    = (float*)alloc(4L * 128 * 4);
  u16* lcbf    = (u16*)alloc(4L * T_IN * 128 * 2);
  u16* xA      = (u16*)alloc(4L * T_IN * 384 * 2);
  u16* xB      = (u16*)alloc(4L * T_IN * 384 * 2);
  u16* zbuf    = (u16*)alloc(4L * T_IN * 256 * 2);
  float* skip  = (float*)alloc(4L * T_OUT * 256 * 4);
  // lc-chain scratch aliased into zbuf (dead before layer 0 writes zbuf)
  float* lcs0 = (float*)zbuf;
  float* lcs1 = lcs0 + 4L * 128 * 64;
  float* lcs2 = lcs1 + 4L * 128 * 290;
  float* lcs3 = lcs2 + 4L * 128 * 1148;
  (void)ws_size; (void)in_sizes; (void)n_in; (void)out_size;

  // weight packs
  k_pack_frag_gau<<<4480, 256, 0, stream>>>(sig_w, gate_w, psig_w, pgate_w, wfgF, wfgG);
  k_pack_frag<<<1280, 256, 0, stream>>>(skp_w, wskpF, 256, 256, 20, 256L * 256);
  k_pack_frag<<<1920, 256, 0, stream>>>(res_w, wresF, 384, 256, 20, 384L * 256);
  k_f32_to_bf16<<<256, 256, 0, stream>>>(base_w, wbase, 384L * 256);
  k_transpose_pack<<<256, 256, 0, stream>>>(post1_w, wp1T, 512, 256);
  k_transpose_pack<<<256, 256, 0, stream>>>(post2_w, wp2T, 256, 512);
  k_pack_tconv<<<512, 256, 0, stream>>>(ups_w[0], wtc1, 5, 25, 5);
  k_pack_tconv<<<512, 256, 0, stream>>>(ups_w[1], wtc2, 4, 16, 4);
  k_pack_tconv<<<512, 256, 0, stream>>>(ups_w[2], wtc3, 4, 16, 4);
  k_pack_tconv<<<512, 256, 0, stream>>>(ups_w[3], wtc4, 4, 16, 4);
  k_gc<<<1, 512, 0, stream>>>(emb_w, emb_b, spk, gc);
  k_cbias<<<dim3(20, 8), 256, 0, stream>>>(psig_w, pgate_w, sig_b, gate_b, gc, cbias);

  // local-conditioning chain
  k_lc0<<<4, 128, 0, stream>>>(lc_sparse, jit, lc_conv_w, lc_conv_b, lcs0);
  k_tconvg<5, false><<<dim3(1, 10, 4), 256, 0, stream>>>(lcs0, 62, 64, lcs1, 290, 290, wtc1, ups_b[0], 5);
  k_tconvg<4, false><<<dim3(5, 8, 4), 256, 0, stream>>>(lcs1, 290, 290, lcs2, 1148, 1148, wtc2, ups_b[1], 4);
  k_tconvg<4, false><<<dim3(18, 8, 4), 256, 0, stream>>>(lcs2, 1148, 1148, lcs3, 4580, 4580, wtc3, ups_b[2], 4);
  k_tconvg<4, true><<<dim3(72, 8, 4), 256, 0, stream>>>(lcs3, 4580, 4580, lcbf, T_IN, 0, wtc4, ups_b[3], 4);

  // base 1x1 conv -> xA t-major bf16
  k_base<<<dim3(287, 6, 4), 256, 0, stream>>>(wav, wbase, base_b, xA);

  k_zero<<<2048, 256, 0, stream>>>(skip, 4L * T_OUT * 256);

  static const int DILS[20] = {1, 2, 4, 8, 16, 32, 64, 128, 256, 512,
                               1, 2, 4, 8, 16, 32, 64, 128, 256, 512};
  int cum = 0;
  u16* xc = xA; u16* xn = xB;
  const long bzs = (long)T_IN * 256, bxs = (long)T_IN * 384, bss = (long)T_OUT * 256;
  for (int l = 0; l < 20; ++l) {
    int dd = DILS[l], lw = dd, cl = cum + lw;
    int Lx = T_IN - cum, Lz = T_IN - cl;
    int sl = 2046 - cl;
    int tzb = (Lz + 255) / 256;
    k_gaum<<<dim3(tzb, 4, 4), 256, 0, stream>>>(
        xc, lcbf, wfgF + (long)l * 229376, wfgG + (long)l * 229376,
        cbias + (long)l * 2048, zbuf, Lz, Lx, dd, cl);
    k_mgemm<1><<<dim3(64, 4, 4), 256, 0, stream>>>(
        zbuf, bzs, 256, sl, Lz - 1, wskpF + (long)l * 65536, 8,
        nullptr, 0, 0, skip, bss, 256, T_OUT);
    k_mgemm<2><<<dim3(tzb, 6, 4), 256, 0, stream>>>(
        zbuf, bzs, 256, 0, Lz - 1, wresF + (long)l * 98304, 8,
        xc, bxs, lw, xn, bxs, 384, Lz);
    cum = cl;
    u16* t = xc; xc = xn; xn = t;
  }

  k_post<<<dim3((T_OUT + 15) / 16, 4), 256, 0, stream>>>(skip, wp1T, post1_b, wp2T, post2_b, out);
}

// Round 3
// 6735.855 us; speedup vs baseline: 7.4022x; 1.1294x over previous
//
#include <hip/hip_runtime.h>
#include <hip/hip_bf16.h>
#include <math.h>

// WaveNet forward on gfx950 — round 3: all heavy ops on MFMA.
// t-major bf16 activations, fragment-packed weights (mapping verified in r2).

#define T_IN 18308
#define T_OUT 16262

typedef unsigned short u16;
typedef unsigned int u32;
typedef __attribute__((ext_vector_type(8))) short short8_t;
typedef __attribute__((ext_vector_type(4))) float f32x4;

__device__ __forceinline__ float bf2f(u16 h) { return __uint_as_float(((u32)h) << 16); }
__device__ __forceinline__ u16 f2bf(float f) {
  u32 u = __float_as_uint(f);
  return (u16)((u + 0x7fffu + ((u >> 16) & 1u)) >> 16);
}

// ---- MFMA fragment packing ----
// Frag layout per (mt,ks): dst[(mt*nks+ks)*512 + lane*8 + j] = W[mt*16+(lane&15)][ks*32+(lane>>4)*8+j]
__global__ void k_pack_frag(const float* __restrict__ src, u16* __restrict__ dst,
                            int M, int K, int L, long src_lstride) {
  int nks = K >> 5;
  long per = (long)M * K;
  long total = per * L;
  for (long idx = blockIdx.x * (long)blockDim.x + threadIdx.x; idx < total; idx += (long)gridDim.x * blockDim.x) {
    int l = (int)(idx / per); long r = idx - (long)l * per;
    int j = (int)(r & 7); int lane = (int)((r >> 3) & 63); int fid = (int)(r >> 9);
    int ks = fid % nks; int mt = fid / nks;
    int row = mt * 16 + (lane & 15);
    int col = ks * 32 + ((lane >> 4) << 3) + j;
    dst[idx] = f2bf(src[l * src_lstride + (long)row * K + col]);
  }
}

// GAU fused weights: logical W[l][256][896]: k<384 tap0, k<768 tap1, else psig(lc chans 0..127)
__global__ void k_pack_frag_gau(const float* __restrict__ sig_w, const float* __restrict__ gate_w,
                                const float* __restrict__ psig_w, const float* __restrict__ pgate_w,
                                u16* __restrict__ dstF, u16* __restrict__ dstG) {
  const long per = 229376; // 16mt * 28ks * 512
  long total = per * 20;
  for (long idx = blockIdx.x * (long)blockDim.x + threadIdx.x; idx < total; idx += (long)gridDim.x * blockDim.x) {
    int l = (int)(idx / per); long r = idx - (long)l * per;
    int j = (int)(r & 7); int lane = (int)((r >> 3) & 63); int fid = (int)(r >> 9);
    int ks = fid % 28; int mt = fid / 28;
    int row = mt * 16 + (lane & 15);
    int k = ks * 32 + ((lane >> 4) << 3) + j;
    float vF, vG;
    if (k < 384) {
      vF = sig_w[(((long)l * 256 + row) * 384 + k) * 2 + 0];
      vG = gate_w[(((long)l * 256 + row) * 384 + k) * 2 + 0];
    } else if (k < 768) {
      vF = sig_w[(((long)l * 256 + row) * 384 + (k - 384)) * 2 + 1];
      vG = gate_w[(((long)l * 256 + row) * 384 + (k - 384)) * 2 + 1];
    } else {
      vF = psig_w[((long)l * 256 + row) * 256 + (k - 768)];
      vG = pgate_w[((long)l * 256 + row) * 256 + (k - 768)];
    }
    dstF[idx] = f2bf(vF);
    dstG[idx] = f2bf(vG);
  }
}

// tconv per-phase weight pack (f32, stages 1-3): dst[p][i*nk+m][o] = w[i][o][K-1-(S-1-p)-m*S]
__global__ void k_pack_tconv(const float* __restrict__ w, float* __restrict__ dst,
                             int S, int K, int nk) {
  int Ktot = 128 * nk;
  long total = (long)S * Ktot * 128;
  for (long idx = blockIdx.x * (long)blockDim.x + threadIdx.x; idx < total; idx += (long)gridDim.x * blockDim.x) {
    int o = (int)(idx & 127);
    long tmp = idx >> 7;
    int k = (int)(tmp % Ktot);
    int p = (int)(tmp / Ktot);
    int i = k / nk, m = k % nk;
    dst[idx] = w[((long)i * 128 + o) * K + (K - 1 - (S - 1 - p) - m * S)];
  }
}

// stage-4 tconv weights, fragment-packed per phase: M=128, K=512 (k = i*4+m), S=4, KW=16
// w index for (p, i, m): 15 - (3-p) - 4m = 12 + p - 4m
__global__ void k_pack_tc4f(const float* __restrict__ w, u16* __restrict__ dst) {
  const long perp = 65536; // 8mt * 16ks * 512
  long total = perp * 4;
  for (long idx = blockIdx.x * (long)blockDim.x + threadIdx.x; idx < total; idx += (long)gridDim.x * blockDim.x) {
    int p = (int)(idx / perp); long r = idx - (long)p * perp;
    int j = (int)(r & 7); int lane = (int)((r >> 3) & 63); int fid = (int)(r >> 9);
    int ks = fid & 15; int mt = fid >> 4;
    int o = mt * 16 + (lane & 15);
    int k = ks * 32 + ((lane >> 4) << 3) + j;
    int i = k >> 2, m = k & 3;
    dst[idx] = f2bf(w[((long)i * 128 + o) * 16 + (12 + p - 4 * m)]);
  }
}

// im2col for stage-4 tconv input: dst[b][j][i*4+m] = lcs3[b][i][j+m]  (bf16)
__global__ void k_im2col3(const float* __restrict__ lcs3, u16* __restrict__ dst) {
  long total = 4L * 4580 * 512;
  for (long idx = blockIdx.x * (long)blockDim.x + threadIdx.x; idx < total; idx += (long)gridDim.x * blockDim.x) {
    int col = (int)(idx & 511);
    long t2 = idx >> 9;
    int jj = (int)(t2 % 4580);
    int b = (int)(t2 / 4580);
    int i = col >> 2, m = col & 3;
    float v = (jj + m < 4580) ? lcs3[((long)b * 128 + i) * 4580 + jj + m] : 0.0f;
    dst[idx] = f2bf(v);
  }
}

__global__ void k_gc(const float* __restrict__ emb_w, const float* __restrict__ emb_b,
                     const int* __restrict__ spk, float* __restrict__ gc) {
  int i = threadIdx.x + blockIdx.x * blockDim.x;
  if (i < 512) { int b = i / 128, g = i % 128; gc[b * 128 + g] = emb_w[g * 40 + spk[b]] + emb_b[g]; }
}

__global__ void k_cbias(const float* __restrict__ psig_w, const float* __restrict__ pgate_w,
                        const float* __restrict__ sig_b, const float* __restrict__ gate_b,
                        const float* __restrict__ gc, float* __restrict__ cbias) {
  int l = blockIdx.x; int fg = blockIdx.y >> 2; int b = blockIdx.y & 3; int c = threadIdx.x;
  const float* p = fg ? pgate_w : psig_w;
  const float* bb = fg ? gate_b : sig_b;
  float acc = bb[l * 256 + c];
  const float* prow = p + ((long)(l * 256 + c)) * 256 + 128;
  const float* g = gc + b * 128;
  for (int k = 0; k < 128; ++k) acc += prow[k] * g[k];
  cbias[((l * 2 + fg) * 4 + b) * 256 + c] = acc;
}

// jitter-gather + conv3 (VALID): out (B,128,62) f32 ch-major, stride 64
__global__ void k_lc0(const float* __restrict__ lc_sparse, const int* __restrict__ jit,
                      const float* __restrict__ w, const float* __restrict__ bias, float* __restrict__ out) {
  int b = blockIdx.x; int co = threadIdx.x;
  __shared__ float xs[64][65];
  for (int i = threadIdx.x; i < 64 * 64; i += blockDim.x) {
    int ci = i >> 6, s = i & 63;
    xs[ci][s] = lc_sparse[((long)b * 64 + ci) * 64 + jit[b * 64 + s]];
  }
  __syncthreads();
  for (int t = 0; t < 62; ++t) {
    float acc = bias[co];
    for (int ci = 0; ci < 64; ++ci) {
      const float* wr = w + ((long)co * 64 + ci) * 3;
      acc += wr[0] * xs[ci][t] + wr[1] * xs[ci][t + 1] + wr[2] * xs[ci][t + 2];
    }
    out[((long)b * 128 + co) * 64 + t] = acc;
  }
}

// Transposed conv stages 1-3 (f32 tiled GEMM, small) — out f32 ch-major
template<int NK>
__global__ __launch_bounds__(256) void k_tconvg(
    const float* __restrict__ xin, int Lin, int xstride,
    float* __restrict__ yout, int Lout, int ostride,
    const float* __restrict__ wp, const float* __restrict__ bias, int S) {
  const int Ktot = 128 * NK;
  __shared__ __align__(16) float Ws[32][64];
  __shared__ __align__(16) float Xs[32][64];
  int b = blockIdx.z;
  int p = blockIdx.y >> 1, bm0 = (blockIdx.y & 1) * 64;
  int j0 = blockIdx.x * 64;
  int tid = threadIdx.x, tn = tid & 15, tm = tid >> 4;
  float acc[4][4] = {};
  int kchunks = Ktot / 32;
  for (int kc = 0; kc < kchunks; ++kc) {
    int k0 = kc * 32;
    {
      int kk = tid >> 3, m8 = (tid & 7) * 8;
      const float* src = wp + ((long)p * Ktot + k0 + kk) * 128 + bm0 + m8;
      float4 f1 = *(const float4*)src;
      float4 f2 = *(const float4*)(src + 4);
      Ws[kk][m8 + 0] = f1.x; Ws[kk][m8 + 1] = f1.y; Ws[kk][m8 + 2] = f1.z; Ws[kk][m8 + 3] = f1.w;
      Ws[kk][m8 + 4] = f2.x; Ws[kk][m8 + 5] = f2.y; Ws[kk][m8 + 6] = f2.z; Ws[kk][m8 + 7] = f2.w;
    }
    #pragma unroll
    for (int rr = 0; rr < 8; ++rr) {
      int kk = rr * 4 + (tid >> 6), tt = tid & 63;
      int k = k0 + kk;
      int i = k / NK, m = k % NK;
      int j = j0 + tt;
      Xs[kk][tt] = (j + m < Lin) ? xin[((long)(b * 128 + i)) * xstride + j + m] : 0.0f;
    }
    __syncthreads();
    #pragma unroll 8
    for (int kk = 0; kk < 32; ++kk) {
      float av[4], bv[4];
      #pragma unroll
      for (int i = 0; i < 4; ++i) av[i] = Ws[kk][tm * 4 + i];
      #pragma unroll
      for (int j = 0; j < 4; ++j) bv[j] = Xs[kk][tn * 4 + j];
      #pragma unroll
      for (int i = 0; i < 4; ++i)
        #pragma unroll
        for (int j = 0; j < 4; ++j) acc[i][j] = fmaf(av[i], bv[j], acc[i][j]);
    }
    __syncthreads();
  }
  #pragma unroll
  for (int jj = 0; jj < 4; ++jj) {
    int j = j0 + tn * 4 + jj;
    int t = j * S + p;
    if (t >= Lout) continue;
    #pragma unroll
    for (int i = 0; i < 4; ++i) {
      int o = bm0 + tm * 4 + i;
      yout[((long)b * 128 + o) * ostride + t] = acc[i][jj] + bias[o];
    }
  }
}

// stage-4 tconv via MFMA: B = im2col [b][j][512], per-phase packed W, out lcbf [b][t=4j+p][128]
__global__ __launch_bounds__(256) void k_tconv4m(
    const u16* __restrict__ im, const u16* __restrict__ Wp4,
    const float* __restrict__ bias, u16* __restrict__ out) {
  int lane = threadIdx.x & 63, wave = threadIdx.x >> 6;
  int b = blockIdx.z;
  int p = blockIdx.y >> 1, chb = (blockIdx.y & 1) << 6;
  int tbase = (blockIdx.x << 8) + (wave << 6);
  int lrow = lane & 15, lk = (lane >> 4) << 3;
  int mt0 = chb >> 4;
  const u16* Wp = Wp4 + (long)p * 65536;
  f32x4 zed = {0.f, 0.f, 0.f, 0.f};
  f32x4 acc[4][4];
  #pragma unroll
  for (int m = 0; m < 4; ++m)
    #pragma unroll
    for (int n = 0; n < 4; ++n) acc[m][n] = zed;
  const u16* ib = im + (long)b * 4580 * 512;
  for (int ks = 0; ks < 16; ++ks) {
    short8_t a[4];
    #pragma unroll
    for (int m = 0; m < 4; ++m)
      a[m] = *(const short8_t*)(Wp + ((long)((mt0 + m) * 16 + ks) << 9) + (lane << 3));
    #pragma unroll
    for (int n = 0; n < 4; ++n) {
      int j = tbase + (n << 4) + lrow;
      j = min(j, 4579);
      short8_t bv = *(const short8_t*)(ib + (long)j * 512 + (ks << 5) + lk);
      #pragma unroll
      for (int m = 0; m < 4; ++m)
        acc[m][n] = __builtin_amdgcn_mfma_f32_16x16x32_bf16(a[m], bv, acc[m][n], 0, 0, 0);
    }
  }
  #pragma unroll
  for (int n = 0; n < 4; ++n) {
    int j = tbase + (n << 4) + lrow;
    int t = j * 4 + p;
    if (t >= T_IN) continue;
    #pragma unroll
    for (int m = 0; m < 4; ++m) {
      int ch0 = chb + (m << 4) + ((lane >> 4) << 2);
      f32x4 bb = *(const f32x4*)(bias + ch0);
      ushort4 o;
      o.x = f2bf(acc[m][n][0] + bb[0]);
      o.y = f2bf(acc[m][n][1] + bb[1]);
      o.z = f2bf(acc[m][n][2] + bb[2]);
      o.w = f2bf(acc[m][n][3] + bb[3]);
      *(ushort4*)(out + ((long)b * T_IN + t) * 128 + ch0) = o;
    }
  }
}

// wav transpose: f32 ch-major [b][256][T] -> bf16 t-major [b][T][256]
__global__ __launch_bounds__(256) void k_wav_t(const float* __restrict__ wav, u16* __restrict__ dst) {
  __shared__ float xs[32][65];
  int b = blockIdx.z, c0 = blockIdx.y * 32, t0 = blockIdx.x * 64;
  int tid = threadIdx.x;
  #pragma unroll
  for (int i = 0; i < 8; ++i) {
    int idx = tid + i * 256;
    int c = idx >> 6, tl = idx & 63;
    int t = t0 + tl; if (t >= T_IN) t = T_IN - 1;
    xs[c][tl] = wav[((long)b * 256 + c0 + c) * T_IN + t];
  }
  __syncthreads();
  #pragma unroll
  for (int i = 0; i < 8; ++i) {
    int idx = tid + i * 256;
    int tl = idx >> 5, c = idx & 31;
    int t = t0 + tl;
    if (t < T_IN) dst[((long)b * T_IN + t) * 256 + c0 + c] = f2bf(xs[c][tl]);
  }
}

// base 1x1 conv MFMA: M=384, K=256, B = wavT, out xA bf16 t-major [b][t][384]
__global__ __launch_bounds__(256) void k_basem(
    const u16* __restrict__ wavT, const u16* __restrict__ Wp,
    const float* __restrict__ bias, u16* __restrict__ X) {
  int lane = threadIdx.x & 63, wave = threadIdx.x >> 6;
  int b = blockIdx.z, chb = blockIdx.y << 6;
  int tbase = (blockIdx.x << 8) + (wave << 6);
  int lrow = lane & 15, lk = (lane >> 4) << 3;
  int mt0 = chb >> 4;
  f32x4 zed = {0.f, 0.f, 0.f, 0.f};
  f32x4 acc[4][4];
  #pragma unroll
  for (int m = 0; m < 4; ++m)
    #pragma unroll
    for (int n = 0; n < 4; ++n) acc[m][n] = zed;
  const u16* xb = wavT + (long)b * T_IN * 256;
  for (int ks = 0; ks < 8; ++ks) {
    short8_t a[4];
    #pragma unroll
    for (int m = 0; m < 4; ++m)
      a[m] = *(const short8_t*)(Wp + ((long)((mt0 + m) * 8 + ks) << 9) + (lane << 3));
    #pragma unroll
    for (int n = 0; n < 4; ++n) {
      int row = tbase + (n << 4) + lrow;
      row = min(row, T_IN - 1);
      short8_t bv = *(const short8_t*)(xb + (long)row * 256 + (ks << 5) + lk);
      #pragma unroll
      for (int m = 0; m < 4; ++m)
        acc[m][n] = __builtin_amdgcn_mfma_f32_16x16x32_bf16(a[m], bv, acc[m][n], 0, 0, 0);
    }
  }
  #pragma unroll
  for (int n = 0; n < 4; ++n) {
    int t = tbase + (n << 4) + lrow;
    if (t >= T_IN) continue;
    #pragma unroll
    for (int m = 0; m < 4; ++m) {
      int ch0 = chb + (m << 4) + ((lane >> 4) << 2);
      f32x4 bb = *(const f32x4*)(bias + ch0);
      ushort4 o;
      o.x = f2bf(acc[m][n][0] + bb[0]);
      o.y = f2bf(acc[m][n][1] + bb[1]);
      o.z = f2bf(acc[m][n][2] + bb[2]);
      o.w = f2bf(acc[m][n][3] + bb[3]);
      *(ushort4*)(X + ((long)b * T_IN + t) * 384 + ch0) = o;
    }
  }
}

// GAU: dual F/G accumulators, segmented K (tap0/tap1/cond), fused activation -> z bf16 t-major
__global__ __launch_bounds__(256) void k_gaum(
    const u16* __restrict__ Xc, const u16* __restrict__ Lc,
    const u16* __restrict__ WpF, const u16* __restrict__ WpG,
    const float* __restrict__ cb, u16* __restrict__ Z,
    int Lz, int Lx, int d, int cl) {
  int lane = threadIdx.x & 63, wave = threadIdx.x >> 6;
  int b = blockIdx.z, chb = blockIdx.y << 6;
  int tbase = (blockIdx.x << 8) + (wave << 6);
  int lrow = lane & 15, lk = (lane >> 4) << 3;
  int mt0 = chb >> 4;
  const long bxs = (long)T_IN * 384, blcs = (long)T_IN * 128, bzs = (long)T_IN * 256;
  f32x4 zed = {0.f, 0.f, 0.f, 0.f};
  f32x4 accF[4][4], accG[4][4];
  #pragma unroll
  for (int m = 0; m < 4; ++m)
    #pragma unroll
    for (int n = 0; n < 4; ++n) { accF[m][n] = zed; accG[m][n] = zed; }
  const u16* xb = Xc + (long)b * bxs;
  const u16* lb = Lc + (long)b * blcs;
  for (int ks = 0; ks < 28; ++ks) {
    short8_t af[4], ag[4];
    #pragma unroll
    for (int m = 0; m < 4; ++m) {
      long fo = ((long)((mt0 + m) * 28 + ks) << 9) + (lane << 3);
      af[m] = *(const short8_t*)(WpF + fo);
      ag[m] = *(const short8_t*)(WpG + fo);
    }
    const u16* src; int koff, rowadd, ldB, clampv;
    if (ks < 12)      { src = xb; koff = ks * 32;        rowadd = 0;  ldB = 384; clampv = Lx - 1; }
    else if (ks < 24) { src = xb; koff = ks * 32 - 384;  rowadd = d;  ldB = 384; clampv = Lx - 1; }
    else              { src = lb; koff = ks * 32 - 768;  rowadd = cl; ldB = 128; clampv = T_IN - 1; }
    #pragma unroll
    for (int n = 0; n < 4; ++n) {
      int row = tbase + (n << 4) + lrow + rowadd;
      row = min(row, clampv);
      short8_t bv = *(const short8_t*)(src + (long)row * ldB + koff + lk);
      #pragma unroll
      for (int m = 0; m < 4; ++m) {
        accF[m][n] = __builtin_amdgcn_mfma_f32_16x16x32_bf16(af[m], bv, accF[m][n], 0, 0, 0);
        accG[m][n] = __builtin_amdgcn_mfma_f32_16x16x32_bf16(ag[m], bv, accG[m][n], 0, 0, 0);
      }
    }
  }
  const float* cbF = cb + b * 256;
  const float* cbG = cb + 1024 + b * 256;
  #pragma unroll
  for (int n = 0; n < 4; ++n) {
    int t = tbase + (n << 4) + lrow;
    if (t >= Lz) continue;
    #pragma unroll
    for (int m = 0; m < 4; ++m) {
      int ch0 = chb + (m << 4) + ((lane >> 4) << 2);
      f32x4 bf = *(const f32x4*)(cbF + ch0);
      f32x4 bg = *(const f32x4*)(cbG + ch0);
      ushort4 o;
      #pragma unroll
      for (int r = 0; r < 4; ++r) {
        float f = accF[m][n][r] + bf[r];
        float g = accG[m][n][r] + bg[r];
        f = fminf(fmaxf(f, -15.f), 15.f);
        float e2 = __expf(2.f * f);
        float th = 1.f - 2.f * __builtin_amdgcn_rcpf(e2 + 1.f);
        float sg = __builtin_amdgcn_rcpf(1.f + __expf(-g));
        u16 zz = f2bf(th * sg);
        if (r == 0) o.x = zz; else if (r == 1) o.y = zz; else if (r == 2) o.z = zz; else o.w = zz;
      }
      *(ushort4*)(Z + (long)b * bzs + (long)t * 256 + ch0) = o;
    }
  }
}

// Fused skip+res: grid.y 0-3 => skip (M=256, f32 accum at t=i-sl), 4-9 => res (M=384, +residual)
__global__ __launch_bounds__(256) void k_skipres(
    const u16* __restrict__ Z, const u16* __restrict__ Wskp, const u16* __restrict__ Wres,
    const u16* __restrict__ Xres, float* __restrict__ skip, u16* __restrict__ Xout,
    int Lz, int sl, int lw, int first) {
  int lane = threadIdx.x & 63, wave = threadIdx.x >> 6;
  int b = blockIdx.z;
  bool isres = blockIdx.y >= 4;
  int chb = (isres ? (blockIdx.y - 4) : blockIdx.y) << 6;
  const u16* Wp = isres ? Wres : Wskp;
  int tbase = (blockIdx.x << 8) + (wave << 6);
  int lrow = lane & 15, lk = (lane >> 4) << 3;
  int mt0 = chb >> 4;
  f32x4 zed = {0.f, 0.f, 0.f, 0.f};
  f32x4 acc[4][4];
  #pragma unroll
  for (int m = 0; m < 4; ++m)
    #pragma unroll
    for (int n = 0; n < 4; ++n) acc[m][n] = zed;
  const u16* zb = Z + (long)b * T_IN * 256;
  for (int ks = 0; ks < 8; ++ks) {
    short8_t a[4];
    #pragma unroll
    for (int m = 0; m < 4; ++m)
      a[m] = *(const short8_t*)(Wp + ((long)((mt0 + m) * 8 + ks) << 9) + (lane << 3));
    #pragma unroll
    for (int n = 0; n < 4; ++n) {
      int row = tbase + (n << 4) + lrow;
      row = min(row, Lz - 1);
      short8_t bv = *(const short8_t*)(zb + (long)row * 256 + (ks << 5) + lk);
      #pragma unroll
      for (int m = 0; m < 4; ++m)
        acc[m][n] = __builtin_amdgcn_mfma_f32_16x16x32_bf16(a[m], bv, acc[m][n], 0, 0, 0);
    }
  }
  #pragma unroll
  for (int n = 0; n < 4; ++n) {
    int i = tbase + (n << 4) + lrow;
    #pragma unroll
    for (int m = 0; m < 4; ++m) {
      int ch0 = chb + (m << 4) + ((lane >> 4) << 2);
      if (!isres) {
        int t = i - sl;
        if (i >= sl && i < Lz) {
          float* p = skip + ((long)b * T_OUT + t) * 256 + ch0;
          if (first) { *(f32x4*)p = acc[m][n]; }
          else { f32x4 v = *(f32x4*)p; v += acc[m][n]; *(f32x4*)p = v; }
        }
      } else if (i < Lz) {
        const u16* rp = Xres + ((long)b * T_IN + i + lw) * 384 + ch0;
        ushort4 rv = *(const ushort4*)rp;
        ushort4 o;
        o.x = f2bf(acc[m][n][0] + bf2f(rv.x));
        o.y = f2bf(acc[m][n][1] + bf2f(rv.y));
        o.z = f2bf(acc[m][n][2] + bf2f(rv.z));
        o.w = f2bf(acc[m][n][3] + bf2f(rv.w));
        *(ushort4*)(Xout + ((long)b * T_IN + i) * 384 + ch0) = o;
      }
    }
  }
}

// post1: h1 = relu(W1 @ relu(skip) + b1), M=512, K=256; B from f32 skip with inline relu+cvt
__global__ __launch_bounds__(256) void k_post1(
    const float* __restrict__ skip, const u16* __restrict__ Wp,
    const float* __restrict__ b1, u16* __restrict__ h1) {
  int lane = threadIdx.x & 63, wave = threadIdx.x >> 6;
  int b = blockIdx.z, qb = blockIdx.y << 6;
  int tbase = (blockIdx.x << 8) + (wave << 6);
  int lrow = lane & 15, lk = (lane >> 4) << 3;
  int mt0 = qb >> 4;
  f32x4 zed = {0.f, 0.f, 0.f, 0.f};
  f32x4 acc[4][4];
  #pragma unroll
  for (int m = 0; m < 4; ++m)
    #pragma unroll
    for (int n = 0; n < 4; ++n) acc[m][n] = zed;
  const float* sb = skip + (long)b * T_OUT * 256;
  for (int ks = 0; ks < 8; ++ks) {
    short8_t a[4];
    #pragma unroll
    for (int m = 0; m < 4; ++m)
      a[m] = *(const short8_t*)(Wp + ((long)((mt0 + m) * 8 + ks) << 9) + (lane << 3));
    #pragma unroll
    for (int n = 0; n < 4; ++n) {
      int row = tbase + (n << 4) + lrow;
      row = min(row, T_OUT - 1);
      const float* src = sb + (long)row * 256 + (ks << 5) + lk;
      f32x4 v0 = *(const f32x4*)src;
      f32x4 v1 = *(const f32x4*)(src + 4);
      short8_t bv;
      #pragma unroll
      for (int j = 0; j < 4; ++j) bv[j] = (short)f2bf(fmaxf(v0[j], 0.f));
      #pragma unroll
      for (int j = 0; j < 4; ++j) bv[4 + j] = (short)f2bf(fmaxf(v1[j], 0.f));
      #pragma unroll
      for (int m = 0; m < 4; ++m)
        acc[m][n] = __builtin_amdgcn_mfma_f32_16x16x32_bf16(a[m], bv, acc[m][n], 0, 0, 0);
    }
  }
  #pragma unroll
  for (int n = 0; n < 4; ++n) {
    int t = tbase + (n << 4) + lrow;
    if (t >= T_OUT) continue;
    #pragma unroll
    for (int m = 0; m < 4; ++m) {
      int ch0 = qb + (m << 4) + ((lane >> 4) << 2);
      f32x4 bb = *(const f32x4*)(b1 + ch0);
      ushort4 o;
      o.x = f2bf(fmaxf(acc[m][n][0] + bb[0], 0.f));
      o.y = f2bf(fmaxf(acc[m][n][1] + bb[1], 0.f));
      o.z = f2bf(fmaxf(acc[m][n][2] + bb[2], 0.f));
      o.w = f2bf(fmaxf(acc[m][n][3] + bb[3], 0.f));
      *(ushort4*)(h1 + ((long)b * T_OUT + t) * 512 + ch0) = o;
    }
  }
}

// post2 + log_softmax: M=256 (all q in one block: 4 waves x 64q), K=512, out f32 [b][q][T_OUT]
__global__ __launch_bounds__(256) void k_post2sm(
    const u16* __restrict__ h1, const u16* __restrict__ Wp,
    const float* __restrict__ b2, float* __restrict__ out) {
  __shared__ float redM[4][64];
  __shared__ float redS[4][64];
  int lane = threadIdx.x & 63, wave = threadIdx.x >> 6;
  int b = blockIdx.z;
  int qb = wave << 6;
  int tb = blockIdx.x << 6;
  int lrow = lane & 15, lk = (lane >> 4) << 3;
  int mt0 = qb >> 4;
  f32x4 zed = {0.f, 0.f, 0.f, 0.f};
  f32x4 acc[4][4];
  #pragma unroll
  for (int m = 0; m < 4; ++m)
    #pragma unroll
    for (int n = 0; n < 4; ++n) acc[m][n] = zed;
  const u16* hb = h1 + (long)b * T_OUT * 512;
  for (int ks = 0; ks < 16; ++ks) {
    short8_t a[4];
    #pragma unroll
    for (int m = 0; m < 4; ++m)
      a[m] = *(const short8_t*)(Wp + ((long)((mt0 + m) * 16 + ks) << 9) + (lane << 3));
    #pragma unroll
    for (int n = 0; n < 4; ++n) {
      int row = tb + (n << 4) + lrow;
      row = min(row, T_OUT - 1);
      short8_t bv = *(const short8_t*)(hb + (long)row * 512 + (ks << 5) + lk);
      #pragma unroll
      for (int m = 0; m < 4; ++m)
        acc[m][n] = __builtin_amdgcn_mfma_f32_16x16x32_bf16(a[m], bv, acc[m][n], 0, 0, 0);
    }
  }
  // add bias
  #pragma unroll
  for (int m = 0; m < 4; ++m) {
    int q0 = qb + (m << 4) + ((lane >> 4) << 2);
    f32x4 bb = *(const f32x4*)(b2 + q0);
    #pragma unroll
    for (int n = 0; n < 4; ++n) acc[m][n] += bb;
  }
  // log-softmax over q (256) per t
  float fm[4], fs[4];
  #pragma unroll
  for (int n = 0; n < 4; ++n) {
    float pm = -1e30f;
    #pragma unroll
    for (int m = 0; m < 4; ++m)
      #pragma unroll
      for (int r = 0; r < 4; ++r) pm = fmaxf(pm, acc[m][n][r]);
    pm = fmaxf(pm, __shfl_xor(pm, 16));
    pm = fmaxf(pm, __shfl_xor(pm, 32));
    if (lane < 16) redM[wave][(n << 4) + lane] = pm;
  }
  __syncthreads();
  #pragma unroll
  for (int n = 0; n < 4; ++n) {
    float mm = redM[0][(n << 4) + lrow];
    mm = fmaxf(mm, redM[1][(n << 4) + lrow]);
    mm = fmaxf(mm, redM[2][(n << 4) + lrow]);
    mm = fmaxf(mm, redM[3][(n << 4) + lrow]);
    fm[n] = mm;
    float ps = 0.f;
    #pragma unroll
    for (int m = 0; m < 4; ++m)
      #pragma unroll
      for (int r = 0; r < 4; ++r) ps += __expf(acc[m][n][r] - mm);
    ps += __shfl_xor(ps, 16);
    ps += __shfl_xor(ps, 32);
    if (lane < 16) redS[wave][(n << 4) + lane] = ps;
  }
  __syncthreads();
  #pragma unroll
  for (int n = 0; n < 4; ++n) {
    float ss = redS[0][(n << 4) + lrow] + redS[1][(n << 4) + lrow] +
               redS[2][(n << 4) + lrow] + redS[3][(n << 4) + lrow];
    fs[n] = fm[n] + logf(ss);
  }
  #pragma unroll
  for (int n = 0; n < 4; ++n) {
    int t = tb + (n << 4) + lrow;
    if (t >= T_OUT) continue;
    #pragma unroll
    for (int m = 0; m < 4; ++m) {
      int q0 = qb + (m << 4) + ((lane >> 4) << 2);
      #pragma unroll
      for (int r = 0; r < 4; ++r)
        out[((long)b * 256 + q0 + r) * T_OUT + t] = acc[m][n][r] - fs[n];
    }
  }
}

extern "C" void kernel_launch(void* const* d_in, const int* in_sizes, int n_in,
                              void* d_out, int out_size, void* d_ws, size_t ws_size,
                              hipStream_t stream) {
  const float* wav       = (const float*)d_in[0];
  const float* lc_sparse = (const float*)d_in[1];
  const float* lc_conv_w = (const float*)d_in[2];
  const float* lc_conv_b = (const float*)d_in[3];
  const float* ups_w[4]  = {(const float*)d_in[4], (const float*)d_in[6], (const float*)d_in[8], (const float*)d_in[10]};
  const float* ups_b[4]  = {(const float*)d_in[5], (const float*)d_in[7], (const float*)d_in[9], (const float*)d_in[11]};
  const float* emb_w     = (const float*)d_in[12];
  const float* emb_b     = (const float*)d_in[13];
  const float* base_w    = (const float*)d_in[14];
  const float* base_b    = (const float*)d_in[15];
  const float* sig_w     = (const float*)d_in[16];
  const float* sig_b     = (const float*)d_in[17];
  const float* gate_w    = (const float*)d_in[18];
  const float* gate_b    = (const float*)d_in[19];
  const float* psig_w    = (const float*)d_in[20];
  const float* pgate_w   = (const float*)d_in[21];
  const float* skp_w     = (const float*)d_in[22];
  const float* res_w     = (const float*)d_in[23];
  const float* post1_w   = (const float*)d_in[24];
  const float* post1_b   = (const float*)d_in[25];
  const float* post2_w   = (const float*)d_in[26];
  const float* post2_b   = (const float*)d_in[27];
  const int* spk         = (const int*)d_in[28];
  const int* jit         = (const int*)d_in[29];
  float* out = (float*)d_out;

  size_t off = 0;
  auto alloc = [&](size_t bytes) -> void* {
    off = (off + 255) & ~(size_t)255;
    void* p = (char*)d_ws + off;
    off += bytes;
    return p;
  };
  u16* wfgF   = (u16*)alloc(20L * 229376 * 2);
  u16* wfgG   = (u16*)alloc(20L * 229376 * 2);
  u16* wskpF  = (u16*)alloc(20L * 65536 * 2);
  u16* wresF  = (u16*)alloc(20L * 98304 * 2);
  u16* wbaseF = (u16*)alloc(384L * 256 * 2);
  u16* wp1F   = (u16*)alloc(512L * 256 * 2);
  u16* wp2F   = (u16*)alloc(256L * 512 * 2);
  float* wtc1 = (float*)alloc(5L * 640 * 128 * 4);
  float* wtc2 = (float*)alloc(4L * 512 * 128 * 4);
  float* wtc3 = (float*)alloc(4L * 512 * 128 * 4);
  u16* wtc4F  = (u16*)alloc(4L * 65536 * 2);
  float* cbias = (float*)alloc(20L * 2 * 4 * 256 * 4);
  float* gc    = (float*)alloc(4L * 128 * 4);
  u16* lcbf    = (u16*)alloc(4L * T_IN * 128 * 2);
  u16* xA      = (u16*)alloc(4L * T_IN * 384 * 2);
  u16* xB      = (u16*)alloc(4L * T_IN * 384 * 2);
  u16* zbuf    = (u16*)alloc(4L * T_IN * 256 * 2);
  float* skip  = (float*)alloc(4L * T_OUT * 256 * 4);
  // temporal aliases (stream-ordered, lifetimes disjoint):
  float* lcs0 = (float*)zbuf;                   // lc scratch lives in zbuf until layer 0
  float* lcs1 = lcs0 + 4L * 128 * 64;
  float* lcs2 = lcs1 + 4L * 128 * 290;
  float* lcs3 = lcs2 + 4L * 128 * 1148;
  u16* im3    = xB;                             // im2col dead before layer-0 res writes xB
  u16* wavT   = (u16*)skip;                     // dead before layer-0 skip write (first=1)
  u16* h1bf   = xA;                             // spans xA..zbuf, used only after layer loop
  (void)ws_size; (void)in_sizes; (void)n_in; (void)out_size;

  // weight packs
  k_pack_frag_gau<<<4480, 256, 0, stream>>>(sig_w, gate_w, psig_w, pgate_w, wfgF, wfgG);
  k_pack_frag<<<1280, 256, 0, stream>>>(skp_w, wskpF, 256, 256, 20, 256L * 256);
  k_pack_frag<<<1920, 256, 0, stream>>>(res_w, wresF, 384, 256, 20, 384L * 256);
  k_pack_frag<<<96, 256, 0, stream>>>(base_w, wbaseF, 384, 256, 1, 0);
  k_pack_frag<<<128, 256, 0, stream>>>(post1_w, wp1F, 512, 256, 1, 0);
  k_pack_frag<<<128, 256, 0, stream>>>(post2_w, wp2F, 256, 512, 1, 0);
  k_pack_tconv<<<320, 256, 0, stream>>>(ups_w[0], wtc1, 5, 25, 5);
  k_pack_tconv<<<256, 256, 0, stream>>>(ups_w[1], wtc2, 4, 16, 4);
  k_pack_tconv<<<256, 256, 0, stream>>>(ups_w[2], wtc3, 4, 16, 4);
  k_pack_tc4f<<<256, 256, 0, stream>>>(ups_w[3], wtc4F);
  k_gc<<<1, 512, 0, stream>>>(emb_w, emb_b, spk, gc);
  k_cbias<<<dim3(20, 8), 256, 0, stream>>>(psig_w, pgate_w, sig_b, gate_b, gc, cbias);

  // local-conditioning chain
  k_lc0<<<4, 128, 0, stream>>>(lc_sparse, jit, lc_conv_w, lc_conv_b, lcs0);
  k_tconvg<5><<<dim3(1, 10, 4), 256, 0, stream>>>(lcs0, 62, 64, lcs1, 290, 290, wtc1, ups_b[0], 5);
  k_tconvg<4><<<dim3(5, 8, 4), 256, 0, stream>>>(lcs1, 290, 290, lcs2, 1148, 1148, wtc2, ups_b[1], 4);
  k_tconvg<4><<<dim3(18, 8, 4), 256, 0, stream>>>(lcs2, 1148, 1148, lcs3, 4580, 4580, wtc3, ups_b[2], 4);
  k_im2col3<<<2048, 256, 0, stream>>>(lcs3, im3);
  k_tconv4m<<<dim3(18, 8, 4), 256, 0, stream>>>(im3, wtc4F, ups_b[3], lcbf);

  // wav transpose + base 1x1 conv (MFMA) -> xA t-major bf16
  k_wav_t<<<dim3(287, 8, 4), 256, 0, stream>>>(wav, wavT);
  k_basem<<<dim3(72, 6, 4), 256, 0, stream>>>(wavT, wbaseF, base_b, xA);

  static const int DILS[20] = {1, 2, 4, 8, 16, 32, 64, 128, 256, 512,
                               1, 2, 4, 8, 16, 32, 64, 128, 256, 512};
  int cum = 0;
  u16* xc = xA; u16* xn = xB;
  for (int l = 0; l < 20; ++l) {
    int dd = DILS[l], lw = dd, cl = cum + lw;
    int Lx = T_IN - cum, Lz = T_IN - cl;
    int sl = 2046 - cl;
    int tzb = (Lz + 255) / 256;
    k_gaum<<<dim3(tzb, 4, 4), 256, 0, stream>>>(
        xc, lcbf, wfgF + (long)l * 229376, wfgG + (long)l * 229376,
        cbias + (long)l * 2048, zbuf, Lz, Lx, dd, cl);
    int gy = (l == 19) ? 4 : 10;
    k_skipres<<<dim3(tzb, gy, 4), 256, 0, stream>>>(
        zbuf, wskpF + (long)l * 65536, wresF + (long)l * 98304,
        xc, skip, xn, Lz, sl, lw, (l == 0) ? 1 : 0);
    cum = cl;
    u16* t = xc; xc = xn; xn = t;
  }

  k_post1<<<dim3(64, 8, 4), 256, 0, stream>>>(skip, wp1F, post1_b, h1bf);
  k_post2sm<<<dim3(255, 1, 4), 256, 0, stream>>>(h1bf, wp2F, post2_b, out);
}

// Round 4
// 5100.238 us; speedup vs baseline: 9.7760x; 1.3207x over previous
//
#include <hip/hip_runtime.h>
#include <hip/hip_bf16.h>
#include <math.h>

// WaveNet forward on gfx950 — round 4: B-operand read-once restructuring.
// gau: 128t x 256ch per block (8 waves, wave=chb x thalf). skipres: 640ch in
// one block (10 waves). lc0 parallelized over t.

#define T_IN 18308
#define T_OUT 16262

typedef unsigned short u16;
typedef unsigned int u32;
typedef __attribute__((ext_vector_type(8))) short short8_t;
typedef __attribute__((ext_vector_type(4))) float f32x4;

__device__ __forceinline__ float bf2f(u16 h) { return __uint_as_float(((u32)h) << 16); }
__device__ __forceinline__ u16 f2bf(float f) {
  u32 u = __float_as_uint(f);
  return (u16)((u + 0x7fffu + ((u >> 16) & 1u)) >> 16);
}

// ---- MFMA fragment packing ----
// Frag layout per (mt,ks): dst[(mt*nks+ks)*512 + lane*8 + j] = W[mt*16+(lane&15)][ks*32+(lane>>4)*8+j]
__global__ void k_pack_frag(const float* __restrict__ src, u16* __restrict__ dst,
                            int M, int K, int L, long src_lstride) {
  int nks = K >> 5;
  long per = (long)M * K;
  long total = per * L;
  for (long idx = blockIdx.x * (long)blockDim.x + threadIdx.x; idx < total; idx += (long)gridDim.x * blockDim.x) {
    int l = (int)(idx / per); long r = idx - (long)l * per;
    int j = (int)(r & 7); int lane = (int)((r >> 3) & 63); int fid = (int)(r >> 9);
    int ks = fid % nks; int mt = fid / nks;
    int row = mt * 16 + (lane & 15);
    int col = ks * 32 + ((lane >> 4) << 3) + j;
    dst[idx] = f2bf(src[l * src_lstride + (long)row * K + col]);
  }
}

// GAU fused weights: logical W[l][256][896]: k<384 tap0, k<768 tap1, else psig(lc chans 0..127)
__global__ void k_pack_frag_gau(const float* __restrict__ sig_w, const float* __restrict__ gate_w,
                                const float* __restrict__ psig_w, const float* __restrict__ pgate_w,
                                u16* __restrict__ dstF, u16* __restrict__ dstG) {
  const long per = 229376; // 16mt * 28ks * 512
  long total = per * 20;
  for (long idx = blockIdx.x * (long)blockDim.x + threadIdx.x; idx < total; idx += (long)gridDim.x * blockDim.x) {
    int l = (int)(idx / per); long r = idx - (long)l * per;
    int j = (int)(r & 7); int lane = (int)((r >> 3) & 63); int fid = (int)(r >> 9);
    int ks = fid % 28; int mt = fid / 28;
    int row = mt * 16 + (lane & 15);
    int k = ks * 32 + ((lane >> 4) << 3) + j;
    float vF, vG;
    if (k < 384) {
      vF = sig_w[(((long)l * 256 + row) * 384 + k) * 2 + 0];
      vG = gate_w[(((long)l * 256 + row) * 384 + k) * 2 + 0];
    } else if (k < 768) {
      vF = sig_w[(((long)l * 256 + row) * 384 + (k - 384)) * 2 + 1];
      vG = gate_w[(((long)l * 256 + row) * 384 + (k - 384)) * 2 + 1];
    } else {
      vF = psig_w[((long)l * 256 + row) * 256 + (k - 768)];
      vG = pgate_w[((long)l * 256 + row) * 256 + (k - 768)];
    }
    dstF[idx] = f2bf(vF);
    dstG[idx] = f2bf(vG);
  }
}

// tconv per-phase weight pack (f32, stages 1-3): dst[p][i*nk+m][o] = w[i][o][K-1-(S-1-p)-m*S]
__global__ void k_pack_tconv(const float* __restrict__ w, float* __restrict__ dst,
                             int S, int K, int nk) {
  int Ktot = 128 * nk;
  long total = (long)S * Ktot * 128;
  for (long idx = blockIdx.x * (long)blockDim.x + threadIdx.x; idx < total; idx += (long)gridDim.x * blockDim.x) {
    int o = (int)(idx & 127);
    long tmp = idx >> 7;
    int k = (int)(tmp % Ktot);
    int p = (int)(tmp / Ktot);
    int i = k / nk, m = k % nk;
    dst[idx] = w[((long)i * 128 + o) * K + (K - 1 - (S - 1 - p) - m * S)];
  }
}

// stage-4 tconv weights, fragment-packed per phase: M=128, K=512 (k = i*4+m), S=4, KW=16
__global__ void k_pack_tc4f(const float* __restrict__ w, u16* __restrict__ dst) {
  const long perp = 65536; // 8mt * 16ks * 512
  long total = perp * 4;
  for (long idx = blockIdx.x * (long)blockDim.x + threadIdx.x; idx < total; idx += (long)gridDim.x * blockDim.x) {
    int p = (int)(idx / perp); long r = idx - (long)p * perp;
    int j = (int)(r & 7); int lane = (int)((r >> 3) & 63); int fid = (int)(r >> 9);
    int ks = fid & 15; int mt = fid >> 4;
    int o = mt * 16 + (lane & 15);
    int k = ks * 32 + ((lane >> 4) << 3) + j;
    int i = k >> 2, m = k & 3;
    dst[idx] = f2bf(w[((long)i * 128 + o) * 16 + (12 + p - 4 * m)]);
  }
}

// im2col for stage-4 tconv input: dst[b][j][i*4+m] = lcs3[b][i][j+m]  (bf16)
__global__ void k_im2col3(const float* __restrict__ lcs3, u16* __restrict__ dst) {
  long total = 4L * 4580 * 512;
  for (long idx = blockIdx.x * (long)blockDim.x + threadIdx.x; idx < total; idx += (long)gridDim.x * blockDim.x) {
    int col = (int)(idx & 511);
    long t2 = idx >> 9;
    int jj = (int)(t2 % 4580);
    int b = (int)(t2 / 4580);
    int i = col >> 2, m = col & 3;
    float v = (jj + m < 4580) ? lcs3[((long)b * 128 + i) * 4580 + jj + m] : 0.0f;
    dst[idx] = f2bf(v);
  }
}

__global__ void k_gc(const float* __restrict__ emb_w, const float* __restrict__ emb_b,
                     const int* __restrict__ spk, float* __restrict__ gc) {
  int i = threadIdx.x + blockIdx.x * blockDim.x;
  if (i < 512) { int b = i / 128, g = i % 128; gc[b * 128 + g] = emb_w[g * 40 + spk[b]] + emb_b[g]; }
}

__global__ void k_cbias(const float* __restrict__ psig_w, const float* __restrict__ pgate_w,
                        const float* __restrict__ sig_b, const float* __restrict__ gate_b,
                        const float* __restrict__ gc, float* __restrict__ cbias) {
  int l = blockIdx.x; int fg = blockIdx.y >> 2; int b = blockIdx.y & 3; int c = threadIdx.x;
  const float* p = fg ? pgate_w : psig_w;
  const float* bb = fg ? gate_b : sig_b;
  float acc = bb[l * 256 + c];
  const float* prow = p + ((long)(l * 256 + c)) * 256 + 128;
  const float* g = gc + b * 128;
  for (int k = 0; k < 128; ++k) acc += prow[k] * g[k];
  cbias[((l * 2 + fg) * 4 + b) * 256 + c] = acc;
}

// jitter-gather + conv3 (VALID): out (B,128,62) f32 ch-major, stride 64
// grid (4, 62): one block per (b, t)
__global__ void k_lc0(const float* __restrict__ lc_sparse, const int* __restrict__ jit,
                      const float* __restrict__ w, const float* __restrict__ bias, float* __restrict__ out) {
  int b = blockIdx.x; int t = blockIdx.y; int co = threadIdx.x; // 128
  __shared__ float xs[64][3];
  for (int i = threadIdx.x; i < 192; i += blockDim.x) {
    int ci = i / 3, kk = i % 3;
    xs[ci][kk] = lc_sparse[((long)b * 64 + ci) * 64 + jit[b * 64 + t + kk]];
  }
  __syncthreads();
  float acc = bias[co];
  #pragma unroll 8
  for (int ci = 0; ci < 64; ++ci) {
    const float* wr = w + ((long)co * 64 + ci) * 3;
    acc += wr[0] * xs[ci][0] + wr[1] * xs[ci][1] + wr[2] * xs[ci][2];
  }
  out[((long)b * 128 + co) * 64 + t] = acc;
}

// Transposed conv stages 1-3 (f32 tiled GEMM, small) — out f32 ch-major
template<int NK>
__global__ __launch_bounds__(256) void k_tconvg(
    const float* __restrict__ xin, int Lin, int xstride,
    float* __restrict__ yout, int Lout, int ostride,
    const float* __restrict__ wp, const float* __restrict__ bias, int S) {
  const int Ktot = 128 * NK;
  __shared__ __align__(16) float Ws[32][64];
  __shared__ __align__(16) float Xs[32][64];
  int b = blockIdx.z;
  int p = blockIdx.y >> 1, bm0 = (blockIdx.y & 1) * 64;
  int j0 = blockIdx.x * 64;
  int tid = threadIdx.x, tn = tid & 15, tm = tid >> 4;
  float acc[4][4] = {};
  int kchunks = Ktot / 32;
  for (int kc = 0; kc < kchunks; ++kc) {
    int k0 = kc * 32;
    {
      int kk = tid >> 3, m8 = (tid & 7) * 8;
      const float* src = wp + ((long)p * Ktot + k0 + kk) * 128 + bm0 + m8;
      float4 f1 = *(const float4*)src;
      float4 f2 = *(const float4*)(src + 4);
      Ws[kk][m8 + 0] = f1.x; Ws[kk][m8 + 1] = f1.y; Ws[kk][m8 + 2] = f1.z; Ws[kk][m8 + 3] = f1.w;
      Ws[kk][m8 + 4] = f2.x; Ws[kk][m8 + 5] = f2.y; Ws[kk][m8 + 6] = f2.z; Ws[kk][m8 + 7] = f2.w;
    }
    #pragma unroll
    for (int rr = 0; rr < 8; ++rr) {
      int kk = rr * 4 + (tid >> 6), tt = tid & 63;
      int k = k0 + kk;
      int i = k / NK, m = k % NK;
      int j = j0 + tt;
      Xs[kk][tt] = (j + m < Lin) ? xin[((long)(b * 128 + i)) * xstride + j + m] : 0.0f;
    }
    __syncthreads();
    #pragma unroll 8
    for (int kk = 0; kk < 32; ++kk) {
      float av[4], bv[4];
      #pragma unroll
      for (int i = 0; i < 4; ++i) av[i] = Ws[kk][tm * 4 + i];
      #pragma unroll
      for (int j = 0; j < 4; ++j) bv[j] = Xs[kk][tn * 4 + j];
      #pragma unroll
      for (int i = 0; i < 4; ++i)
        #pragma unroll
        for (int j = 0; j < 4; ++j) acc[i][j] = fmaf(av[i], bv[j], acc[i][j]);
    }
    __syncthreads();
  }
  #pragma unroll
  for (int jj = 0; jj < 4; ++jj) {
    int j = j0 + tn * 4 + jj;
    int t = j * S + p;
    if (t >= Lout) continue;
    #pragma unroll
    for (int i = 0; i < 4; ++i) {
      int o = bm0 + tm * 4 + i;
      yout[((long)b * 128 + o) * ostride + t] = acc[i][jj] + bias[o];
    }
  }
}

// stage-4 tconv via MFMA: B = im2col [b][j][512], per-phase packed W, out lcbf [b][t=4j+p][128]
__global__ __launch_bounds__(256) void k_tconv4m(
    const u16* __restrict__ im, const u16* __restrict__ Wp4,
    const float* __restrict__ bias, u16* __restrict__ out) {
  int lane = threadIdx.x & 63, wave = threadIdx.x >> 6;
  int b = blockIdx.z;
  int p = blockIdx.y >> 1, chb = (blockIdx.y & 1) << 6;
  int tbase = (blockIdx.x << 8) + (wave << 6);
  int lrow = lane & 15, lk = (lane >> 4) << 3;
  int mt0 = chb >> 4;
  const u16* Wp = Wp4 + (long)p * 65536;
  f32x4 zed = {0.f, 0.f, 0.f, 0.f};
  f32x4 acc[4][4];
  #pragma unroll
  for (int m = 0; m < 4; ++m)
    #pragma unroll
    for (int n = 0; n < 4; ++n) acc[m][n] = zed;
  const u16* ib = im + (long)b * 4580 * 512;
  for (int ks = 0; ks < 16; ++ks) {
    short8_t a[4];
    #pragma unroll
    for (int m = 0; m < 4; ++m)
      a[m] = *(const short8_t*)(Wp + ((long)((mt0 + m) * 16 + ks) << 9) + (lane << 3));
    #pragma unroll
    for (int n = 0; n < 4; ++n) {
      int j = tbase + (n << 4) + lrow;
      j = min(j, 4579);
      short8_t bv = *(const short8_t*)(ib + (long)j * 512 + (ks << 5) + lk);
      #pragma unroll
      for (int m = 0; m < 4; ++m)
        acc[m][n] = __builtin_amdgcn_mfma_f32_16x16x32_bf16(a[m], bv, acc[m][n], 0, 0, 0);
    }
  }
  #pragma unroll
  for (int n = 0; n < 4; ++n) {
    int j = tbase + (n << 4) + lrow;
    int t = j * 4 + p;
    if (t >= T_IN) continue;
    #pragma unroll
    for (int m = 0; m < 4; ++m) {
      int ch0 = chb + (m << 4) + ((lane >> 4) << 2);
      f32x4 bb = *(const f32x4*)(bias + ch0);
      ushort4 o;
      o.x = f2bf(acc[m][n][0] + bb[0]);
      o.y = f2bf(acc[m][n][1] + bb[1]);
      o.z = f2bf(acc[m][n][2] + bb[2]);
      o.w = f2bf(acc[m][n][3] + bb[3]);
      *(ushort4*)(out + ((long)b * T_IN + t) * 128 + ch0) = o;
    }
  }
}

// wav transpose: f32 ch-major [b][256][T] -> bf16 t-major [b][T][256]
__global__ __launch_bounds__(256) void k_wav_t(const float* __restrict__ wav, u16* __restrict__ dst) {
  __shared__ float xs[32][65];
  int b = blockIdx.z, c0 = blockIdx.y * 32, t0 = blockIdx.x * 64;
  int tid = threadIdx.x;
  #pragma unroll
  for (int i = 0; i < 8; ++i) {
    int idx = tid + i * 256;
    int c = idx >> 6, tl = idx & 63;
    int t = t0 + tl; if (t >= T_IN) t = T_IN - 1;
    xs[c][tl] = wav[((long)b * 256 + c0 + c) * T_IN + t];
  }
  __syncthreads();
  #pragma unroll
  for (int i = 0; i < 8; ++i) {
    int idx = tid + i * 256;
    int tl = idx >> 5, c = idx & 31;
    int t = t0 + tl;
    if (t < T_IN) dst[((long)b * T_IN + t) * 256 + c0 + c] = f2bf(xs[c][tl]);
  }
}

// base 1x1 conv MFMA: M=384, K=256, B = wavT, out xA bf16 t-major [b][t][384]
__global__ __launch_bounds__(256) void k_basem(
    const u16* __restrict__ wavT, const u16* __restrict__ Wp,
    const float* __restrict__ bias, u16* __restrict__ X) {
  int lane = threadIdx.x & 63, wave = threadIdx.x >> 6;
  int b = blockIdx.z, chb = blockIdx.y << 6;
  int tbase = (blockIdx.x << 8) + (wave << 6);
  int lrow = lane & 15, lk = (lane >> 4) << 3;
  int mt0 = chb >> 4;
  f32x4 zed = {0.f, 0.f, 0.f, 0.f};
  f32x4 acc[4][4];
  #pragma unroll
  for (int m = 0; m < 4; ++m)
    #pragma unroll
    for (int n = 0; n < 4; ++n) acc[m][n] = zed;
  const u16* xb = wavT + (long)b * T_IN * 256;
  for (int ks = 0; ks < 8; ++ks) {
    short8_t a[4];
    #pragma unroll
    for (int m = 0; m < 4; ++m)
      a[m] = *(const short8_t*)(Wp + ((long)((mt0 + m) * 8 + ks) << 9) + (lane << 3));
    #pragma unroll
    for (int n = 0; n < 4; ++n) {
      int row = tbase + (n << 4) + lrow;
      row = min(row, T_IN - 1);
      short8_t bv = *(const short8_t*)(xb + (long)row * 256 + (ks << 5) + lk);
      #pragma unroll
      for (int m = 0; m < 4; ++m)
        acc[m][n] = __builtin_amdgcn_mfma_f32_16x16x32_bf16(a[m], bv, acc[m][n], 0, 0, 0);
    }
  }
  #pragma unroll
  for (int n = 0; n < 4; ++n) {
    int t = tbase + (n << 4) + lrow;
    if (t >= T_IN) continue;
    #pragma unroll
    for (int m = 0; m < 4; ++m) {
      int ch0 = chb + (m << 4) + ((lane >> 4) << 2);
      f32x4 bb = *(const f32x4*)(bias + ch0);
      ushort4 o;
      o.x = f2bf(acc[m][n][0] + bb[0]);
      o.y = f2bf(acc[m][n][1] + bb[1]);
      o.z = f2bf(acc[m][n][2] + bb[2]);
      o.w = f2bf(acc[m][n][3] + bb[3]);
      *(ushort4*)(X + ((long)b * T_IN + t) * 384 + ch0) = o;
    }
  }
}

// GAU: block = 128t x 256ch, 8 waves (wave = chb x thalf). Dual F/G acc,
// segmented K (tap0/tap1/cond), fused activation -> z bf16 t-major.
__global__ __launch_bounds__(512) void k_gaum(
    const u16* __restrict__ Xc, const u16* __restrict__ Lc,
    const u16* __restrict__ WpF, const u16* __restrict__ WpG,
    const float* __restrict__ cb, u16* __restrict__ Z,
    int Lz, int Lx, int d, int cl) {
  int lane = threadIdx.x & 63, wave = threadIdx.x >> 6;
  int b = blockIdx.z;
  int chb = (wave & 3) << 6;
  int tbase = (blockIdx.x << 7) + ((wave >> 2) << 6);
  int lrow = lane & 15, lk = (lane >> 4) << 3;
  int mt0 = chb >> 4;
  const long bxs = (long)T_IN * 384, blcs = (long)T_IN * 128, bzs = (long)T_IN * 256;
  f32x4 zed = {0.f, 0.f, 0.f, 0.f};
  f32x4 accF[4][4], accG[4][4];
  #pragma unroll
  for (int m = 0; m < 4; ++m)
    #pragma unroll
    for (int n = 0; n < 4; ++n) { accF[m][n] = zed; accG[m][n] = zed; }
  const u16* xb = Xc + (long)b * bxs;
  const u16* lb = Lc + (long)b * blcs;
  for (int ks = 0; ks < 28; ++ks) {
    short8_t af[4], ag[4];
    #pragma unroll
    for (int m = 0; m < 4; ++m) {
      long fo = ((long)((mt0 + m) * 28 + ks) << 9) + (lane << 3);
      af[m] = *(const short8_t*)(WpF + fo);
      ag[m] = *(const short8_t*)(WpG + fo);
    }
    const u16* src; int koff, rowadd, ldB, clampv;
    if (ks < 12)      { src = xb; koff = ks * 32;        rowadd = 0;  ldB = 384; clampv = Lx - 1; }
    else if (ks < 24) { src = xb; koff = ks * 32 - 384;  rowadd = d;  ldB = 384; clampv = Lx - 1; }
    else              { src = lb; koff = ks * 32 - 768;  rowadd = cl; ldB = 128; clampv = T_IN - 1; }
    #pragma unroll
    for (int n = 0; n < 4; ++n) {
      int row = tbase + (n << 4) + lrow + rowadd;
      row = min(row, clampv);
      short8_t bv = *(const short8_t*)(src + (long)row * ldB + koff + lk);
      #pragma unroll
      for (int m = 0; m < 4; ++m) {
        accF[m][n] = __builtin_amdgcn_mfma_f32_16x16x32_bf16(af[m], bv, accF[m][n], 0, 0, 0);
        accG[m][n] = __builtin_amdgcn_mfma_f32_16x16x32_bf16(ag[m], bv, accG[m][n], 0, 0, 0);
      }
    }
  }
  const float* cbF = cb + b * 256;
  const float* cbG = cb + 1024 + b * 256;
  #pragma unroll
  for (int n = 0; n < 4; ++n) {
    int t = tbase + (n << 4) + lrow;
    if (t >= Lz) continue;
    #pragma unroll
    for (int m = 0; m < 4; ++m) {
      int ch0 = chb + (m << 4) + ((lane >> 4) << 2);
      f32x4 bf = *(const f32x4*)(cbF + ch0);
      f32x4 bg = *(const f32x4*)(cbG + ch0);
      ushort4 o;
      #pragma unroll
      for (int r = 0; r < 4; ++r) {
        float f = accF[m][n][r] + bf[r];
        float g = accG[m][n][r] + bg[r];
        f = fminf(fmaxf(f, -15.f), 15.f);
        float e2 = __expf(2.f * f);
        float th = 1.f - 2.f * __builtin_amdgcn_rcpf(e2 + 1.f);
        float sg = __builtin_amdgcn_rcpf(1.f + __expf(-g));
        u16 zz = f2bf(th * sg);
        if (r == 0) o.x = zz; else if (r == 1) o.y = zz; else if (r == 2) o.z = zz; else o.w = zz;
      }
      *(ushort4*)(Z + (long)b * bzs + (long)t * 256 + ch0) = o;
    }
  }
}

// Fused skip+res, all 640 M-channels in one block over 64 t.
// waves 0-3: skip (M=256, f32 accum at t=i-sl); waves 4-9: res (M=384, +residual).
// Launch with 640 threads (256 for last layer: skip only).
__global__ __launch_bounds__(640) void k_skipres(
    const u16* __restrict__ Z, const u16* __restrict__ Wskp, const u16* __restrict__ Wres,
    const u16* __restrict__ Xres, float* __restrict__ skip, u16* __restrict__ Xout,
    int Lz, int sl, int lw, int first) {
  int lane = threadIdx.x & 63, wave = threadIdx.x >> 6;
  int b = blockIdx.z;
  bool isres = wave >= 4;
  int chb = (isres ? (wave - 4) : wave) << 6;
  const u16* Wp = isres ? Wres : Wskp;
  int tbase = blockIdx.x << 6;
  int lrow = lane & 15, lk = (lane >> 4) << 3;
  int mt0 = chb >> 4;
  f32x4 zed = {0.f, 0.f, 0.f, 0.f};
  f32x4 acc[4][4];
  #pragma unroll
  for (int m = 0; m < 4; ++m)
    #pragma unroll
    for (int n = 0; n < 4; ++n) acc[m][n] = zed;
  const u16* zb = Z + (long)b * T_IN * 256;
  for (int ks = 0; ks < 8; ++ks) {
    short8_t a[4];
    #pragma unroll
    for (int m = 0; m < 4; ++m)
      a[m] = *(const short8_t*)(Wp + ((long)((mt0 + m) * 8 + ks) << 9) + (lane << 3));
    #pragma unroll
    for (int n = 0; n < 4; ++n) {
      int row = tbase + (n << 4) + lrow;
      row = min(row, Lz - 1);
      short8_t bv = *(const short8_t*)(zb + (long)row * 256 + (ks << 5) + lk);
      #pragma unroll
      for (int m = 0; m < 4; ++m)
        acc[m][n] = __builtin_amdgcn_mfma_f32_16x16x32_bf16(a[m], bv, acc[m][n], 0, 0, 0);
    }
  }
  #pragma unroll
  for (int n = 0; n < 4; ++n) {
    int i = tbase + (n << 4) + lrow;
    #pragma unroll
    for (int m = 0; m < 4; ++m) {
      int ch0 = chb + (m << 4) + ((lane >> 4) << 2);
      if (!isres) {
        int t = i - sl;
        if (i >= sl && i < Lz) {
          float* p = skip + ((long)b * T_OUT + t) * 256 + ch0;
          if (first) { *(f32x4*)p = acc[m][n]; }
          else { f32x4 v = *(f32x4*)p; v += acc[m][n]; *(f32x4*)p = v; }
        }
      } else if (i < Lz) {
        const u16* rp = Xres + ((long)b * T_IN + i + lw) * 384 + ch0;
        ushort4 rv = *(const ushort4*)rp;
        ushort4 o;
        o.x = f2bf(acc[m][n][0] + bf2f(rv.x));
        o.y = f2bf(acc[m][n][1] + bf2f(rv.y));
        o.z = f2bf(acc[m][n][2] + bf2f(rv.z));
        o.w = f2bf(acc[m][n][3] + bf2f(rv.w));
        *(ushort4*)(Xout + ((long)b * T_IN + i) * 384 + ch0) = o;
      }
    }
  }
}

// post1: h1 = relu(W1 @ relu(skip) + b1), M=512, K=256; B from f32 skip with inline relu+cvt
__global__ __launch_bounds__(256) void k_post1(
    const float* __restrict__ skip, const u16* __restrict__ Wp,
    const float* __restrict__ b1, u16* __restrict__ h1) {
  int lane = threadIdx.x & 63, wave = threadIdx.x >> 6;
  int b = blockIdx.z, qb = blockIdx.y << 6;
  int tbase = (blockIdx.x << 8) + (wave << 6);
  int lrow = lane & 15, lk = (lane >> 4) << 3;
  int mt0 = qb >> 4;
  f32x4 zed = {0.f, 0.f, 0.f, 0.f};
  f32x4 acc[4][4];
  #pragma unroll
  for (int m = 0; m < 4; ++m)
    #pragma unroll
    for (int n = 0; n < 4; ++n) acc[m][n] = zed;
  const float* sb = skip + (long)b * T_OUT * 256;
  for (int ks = 0; ks < 8; ++ks) {
    short8_t a[4];
    #pragma unroll
    for (int m = 0; m < 4; ++m)
      a[m] = *(const short8_t*)(Wp + ((long)((mt0 + m) * 8 + ks) << 9) + (lane << 3));
    #pragma unroll
    for (int n = 0; n < 4; ++n) {
      int row = tbase + (n << 4) + lrow;
      row = min(row, T_OUT - 1);
      const float* src = sb + (long)row * 256 + (ks << 5) + lk;
      f32x4 v0 = *(const f32x4*)src;
      f32x4 v1 = *(const f32x4*)(src + 4);
      short8_t bv;
      #pragma unroll
      for (int j = 0; j < 4; ++j) bv[j] = (short)f2bf(fmaxf(v0[j], 0.f));
      #pragma unroll
      for (int j = 0; j < 4; ++j) bv[4 + j] = (short)f2bf(fmaxf(v1[j], 0.f));
      #pragma unroll
      for (int m = 0; m < 4; ++m)
        acc[m][n] = __builtin_amdgcn_mfma_f32_16x16x32_bf16(a[m], bv, acc[m][n], 0, 0, 0);
    }
  }
  #pragma unroll
  for (int n = 0; n < 4; ++n) {
    int t = tbase + (n << 4) + lrow;
    if (t >= T_OUT) continue;
    #pragma unroll
    for (int m = 0; m < 4; ++m) {
      int ch0 = qb + (m << 4) + ((lane >> 4) << 2);
      f32x4 bb = *(const f32x4*)(b1 + ch0);
      ushort4 o;
      o.x = f2bf(fmaxf(acc[m][n][0] + bb[0], 0.f));
      o.y = f2bf(fmaxf(acc[m][n][1] + bb[1], 0.f));
      o.z = f2bf(fmaxf(acc[m][n][2] + bb[2], 0.f));
      o.w = f2bf(fmaxf(acc[m][n][3] + bb[3], 0.f));
      *(ushort4*)(h1 + ((long)b * T_OUT + t) * 512 + ch0) = o;
    }
  }
}

// post2 + log_softmax: M=256 (4 waves x 64q), K=512, out f32 [b][q][T_OUT]
__global__ __launch_bounds__(256) void k_post2sm(
    const u16* __restrict__ h1, const u16* __restrict__ Wp,
    const float* __restrict__ b2, float* __restrict__ out) {
  __shared__ float redM[4][64];
  __shared__ float redS[4][64];
  int lane = threadIdx.x & 63, wave = threadIdx.x >> 6;
  int b = blockIdx.z;
  int qb = wave << 6;
  int tb = blockIdx.x << 6;
  int lrow = lane & 15, lk = (lane >> 4) << 3;
  int mt0 = qb >> 4;
  f32x4 zed = {0.f, 0.f, 0.f, 0.f};
  f32x4 acc[4][4];
  #pragma unroll
  for (int m = 0; m < 4; ++m)
    #pragma unroll
    for (int n = 0; n < 4; ++n) acc[m][n] = zed;
  const u16* hb = h1 + (long)b * T_OUT * 512;
  for (int ks = 0; ks < 16; ++ks) {
    short8_t a[4];
    #pragma unroll
    for (int m = 0; m < 4; ++m)
      a[m] = *(const short8_t*)(Wp + ((long)((mt0 + m) * 16 + ks) << 9) + (lane << 3));
    #pragma unroll
    for (int n = 0; n < 4; ++n) {
      int row = tb + (n << 4) + lrow;
      row = min(row, T_OUT - 1);
      short8_t bv = *(const short8_t*)(hb + (long)row * 512 + (ks << 5) + lk);
      #pragma unroll
      for (int m = 0; m < 4; ++m)
        acc[m][n] = __builtin_amdgcn_mfma_f32_16x16x32_bf16(a[m], bv, acc[m][n], 0, 0, 0);
    }
  }
  #pragma unroll
  for (int m = 0; m < 4; ++m) {
    int q0 = qb + (m << 4) + ((lane >> 4) << 2);
    f32x4 bb = *(const f32x4*)(b2 + q0);
    #pragma unroll
    for (int n = 0; n < 4; ++n) acc[m][n] += bb;
  }
  float fm[4], fs[4];
  #pragma unroll
  for (int n = 0; n < 4; ++n) {
    float pm = -1e30f;
    #pragma unroll
    for (int m = 0; m < 4; ++m)
      #pragma unroll
      for (int r = 0; r < 4; ++r) pm = fmaxf(pm, acc[m][n][r]);
    pm = fmaxf(pm, __shfl_xor(pm, 16));
    pm = fmaxf(pm, __shfl_xor(pm, 32));
    if (lane < 16) redM[wave][(n << 4) + lane] = pm;
  }
  __syncthreads();
  #pragma unroll
  for (int n = 0; n < 4; ++n) {
    float mm = redM[0][(n << 4) + lrow];
    mm = fmaxf(mm, redM[1][(n << 4) + lrow]);
    mm = fmaxf(mm, redM[2][(n << 4) + lrow]);
    mm = fmaxf(mm, redM[3][(n << 4) + lrow]);
    fm[n] = mm;
    float ps = 0.f;
    #pragma unroll
    for (int m = 0; m < 4; ++m)
      #pragma unroll
      for (int r = 0; r < 4; ++r) ps += __expf(acc[m][n][r] - mm);
    ps += __shfl_xor(ps, 16);
    ps += __shfl_xor(ps, 32);
    if (lane < 16) redS[wave][(n << 4) + lane] = ps;
  }
  __syncthreads();
  #pragma unroll
  for (int n = 0; n < 4; ++n) {
    float ss = redS[0][(n << 4) + lrow] + redS[1][(n << 4) + lrow] +
               redS[2][(n << 4) + lrow] + redS[3][(n << 4) + lrow];
    fs[n] = fm[n] + logf(ss);
  }
  #pragma unroll
  for (int n = 0; n < 4; ++n) {
    int t = tb + (n << 4) + lrow;
    if (t >= T_OUT) continue;
    #pragma unroll
    for (int m = 0; m < 4; ++m) {
      int q0 = qb + (m << 4) + ((lane >> 4) << 2);
      #pragma unroll
      for (int r = 0; r < 4; ++r)
        out[((long)b * 256 + q0 + r) * T_OUT + t] = acc[m][n][r] - fs[n];
    }
  }
}

extern "C" void kernel_launch(void* const* d_in, const int* in_sizes, int n_in,
                              void* d_out, int out_size, void* d_ws, size_t ws_size,
                              hipStream_t stream) {
  const float* wav       = (const float*)d_in[0];
  const float* lc_sparse = (const float*)d_in[1];
  const float* lc_conv_w = (const float*)d_in[2];
  const float* lc_conv_b = (const float*)d_in[3];
  const float* ups_w[4]  = {(const float*)d_in[4], (const float*)d_in[6], (const float*)d_in[8], (const float*)d_in[10]};
  const float* ups_b[4]  = {(const float*)d_in[5], (const float*)d_in[7], (const float*)d_in[9], (const float*)d_in[11]};
  const float* emb_w     = (const float*)d_in[12];
  const float* emb_b     = (const float*)d_in[13];
  const float* base_w    = (const float*)d_in[14];
  const float* base_b    = (const float*)d_in[15];
  const float* sig_w     = (const float*)d_in[16];
  const float* sig_b     = (const float*)d_in[17];
  const float* gate_w    = (const float*)d_in[18];
  const float* gate_b    = (const float*)d_in[19];
  const float* psig_w    = (const float*)d_in[20];
  const float* pgate_w   = (const float*)d_in[21];
  const float* skp_w     = (const float*)d_in[22];
  const float* res_w     = (const float*)d_in[23];
  const float* post1_w   = (const float*)d_in[24];
  const float* post1_b   = (const float*)d_in[25];
  const float* post2_w   = (const float*)d_in[26];
  const float* post2_b   = (const float*)d_in[27];
  const int* spk         = (const int*)d_in[28];
  const int* jit         = (const int*)d_in[29];
  float* out = (float*)d_out;

  size_t off = 0;
  auto alloc = [&](size_t bytes) -> void* {
    off = (off + 255) & ~(size_t)255;
    void* p = (char*)d_ws + off;
    off += bytes;
    return p;
  };
  u16* wfgF   = (u16*)alloc(20L * 229376 * 2);
  u16* wfgG   = (u16*)alloc(20L * 229376 * 2);
  u16* wskpF  = (u16*)alloc(20L * 65536 * 2);
  u16* wresF  = (u16*)alloc(20L * 98304 * 2);
  u16* wbaseF = (u16*)alloc(384L * 256 * 2);
  u16* wp1F   = (u16*)alloc(512L * 256 * 2);
  u16* wp2F   = (u16*)alloc(256L * 512 * 2);
  float* wtc1 = (float*)alloc(5L * 640 * 128 * 4);
  float* wtc2 = (float*)alloc(4L * 512 * 128 * 4);
  float* wtc3 = (float*)alloc(4L * 512 * 128 * 4);
  u16* wtc4F  = (u16*)alloc(4L * 65536 * 2);
  float* cbias = (float*)alloc(20L * 2 * 4 * 256 * 4);
  float* gc    = (float*)alloc(4L * 128 * 4);
  u16* lcbf    = (u16*)alloc(4L * T_IN * 128 * 2);
  u16* xA      = (u16*)alloc(4L * T_IN * 384 * 2);
  u16* xB      = (u16*)alloc(4L * T_IN * 384 * 2);
  u16* zbuf    = (u16*)alloc(4L * T_IN * 256 * 2);
  float* skip  = (float*)alloc(4L * T_OUT * 256 * 4);
  // temporal aliases (stream-ordered, lifetimes disjoint):
  float* lcs0 = (float*)zbuf;
  float* lcs1 = lcs0 + 4L * 128 * 64;
  float* lcs2 = lcs1 + 4L * 128 * 290;
  float* lcs3 = lcs2 + 4L * 128 * 1148;
  u16* im3    = xB;
  u16* wavT   = (u16*)skip;
  u16* h1bf   = xA;
  (void)ws_size; (void)in_sizes; (void)n_in; (void)out_size;

  // weight packs
  k_pack_frag_gau<<<4480, 256, 0, stream>>>(sig_w, gate_w, psig_w, pgate_w, wfgF, wfgG);
  k_pack_frag<<<1280, 256, 0, stream>>>(skp_w, wskpF, 256, 256, 20, 256L * 256);
  k_pack_frag<<<1920, 256, 0, stream>>>(res_w, wresF, 384, 256, 20, 384L * 256);
  k_pack_frag<<<96, 256, 0, stream>>>(base_w, wbaseF, 384, 256, 1, 0);
  k_pack_frag<<<128, 256, 0, stream>>>(post1_w, wp1F, 512, 256, 1, 0);
  k_pack_frag<<<128, 256, 0, stream>>>(post2_w, wp2F, 256, 512, 1, 0);
  k_pack_tconv<<<320, 256, 0, stream>>>(ups_w[0], wtc1, 5, 25, 5);
  k_pack_tconv<<<256, 256, 0, stream>>>(ups_w[1], wtc2, 4, 16, 4);
  k_pack_tconv<<<256, 256, 0, stream>>>(ups_w[2], wtc3, 4, 16, 4);
  k_pack_tc4f<<<256, 256, 0, stream>>>(ups_w[3], wtc4F);
  k_gc<<<1, 512, 0, stream>>>(emb_w, emb_b, spk, gc);
  k_cbias<<<dim3(20, 8), 256, 0, stream>>>(psig_w, pgate_w, sig_b, gate_b, gc, cbias);

  // local-conditioning chain
  k_lc0<<<dim3(4, 62), 128, 0, stream>>>(lc_sparse, jit, lc_conv_w, lc_conv_b, lcs0);
  k_tconvg<5><<<dim3(1, 10, 4), 256, 0, stream>>>(lcs0, 62, 64, lcs1, 290, 290, wtc1, ups_b[0], 5);
  k_tconvg<4><<<dim3(5, 8, 4), 256, 0, stream>>>(lcs1, 290, 290, lcs2, 1148, 1148, wtc2, ups_b[1], 4);
  k_tconvg<4><<<dim3(18, 8, 4), 256, 0, stream>>>(lcs2, 1148, 1148, lcs3, 4580, 4580, wtc3, ups_b[2], 4);
  k_im2col3<<<2048, 256, 0, stream>>>(lcs3, im3);
  k_tconv4m<<<dim3(18, 8, 4), 256, 0, stream>>>(im3, wtc4F, ups_b[3], lcbf);

  // wav transpose + base 1x1 conv (MFMA) -> xA t-major bf16
  k_wav_t<<<dim3(287, 8, 4), 256, 0, stream>>>(wav, wavT);
  k_basem<<<dim3(72, 6, 4), 256, 0, stream>>>(wavT, wbaseF, base_b, xA);

  static const int DILS[20] = {1, 2, 4, 8, 16, 32, 64, 128, 256, 512,
                               1, 2, 4, 8, 16, 32, 64, 128, 256, 512};
  int cum = 0;
  u16* xc = xA; u16* xn = xB;
  for (int l = 0; l < 20; ++l) {
    int dd = DILS[l], lw = dd, cl = cum + lw;
    int Lx = T_IN - cum, Lz = T_IN - cl;
    int sl = 2046 - cl;
    k_gaum<<<dim3((Lz + 127) / 128, 1, 4), 512, 0, stream>>>(
        xc, lcbf, wfgF + (long)l * 229376, wfgG + (long)l * 229376,
        cbias + (long)l * 2048, zbuf, Lz, Lx, dd, cl);
    int nthr = (l == 19) ? 256 : 640;
    k_skipres<<<dim3((Lz + 63) / 64, 1, 4), nthr, 0, stream>>>(
        zbuf, wskpF + (long)l * 65536, wresF + (long)l * 98304,
        xc, skip, xn, Lz, sl, lw, (l == 0) ? 1 : 0);
    cum = cl;
    u16* t = xc; xc = xn; xn = t;
  }

  k_post1<<<dim3(64, 8, 4), 256, 0, stream>>>(skip, wp1F, post1_b, h1bf);
  k_post2sm<<<dim3(255, 1, 4), 256, 0, stream>>>(h1bf, wp2F, post2_b, out);
}

// Round 5
// 4862.071 us; speedup vs baseline: 10.2549x; 1.0490x over previous
//
#include <hip/hip_runtime.h>
#include <hip/hip_bf16.h>
#include <math.h>

// WaveNet forward on gfx950 — round 5: fused per-layer kernel.
// Phase 1: GAU (K=896) with LDS-staged fragment-ordered B (dbuf, 1 barrier/step).
// Phase 2: skip+res GEMMs consume z straight from LDS (XOR-swizzled tile).

#define T_IN 18308
#define T_OUT 16262

typedef unsigned short u16;
typedef unsigned int u32;
typedef __attribute__((ext_vector_type(8))) short short8_t;
typedef __attribute__((ext_vector_type(4))) float f32x4;

__device__ __forceinline__ float bf2f(u16 h) { return __uint_as_float(((u32)h) << 16); }
__device__ __forceinline__ u16 f2bf(float f) {
  u32 u = __float_as_uint(f);
  return (u16)((u + 0x7fffu + ((u >> 16) & 1u)) >> 16);
}

// ---- MFMA fragment packing ----
// Frag layout per (mt,ks): dst[(mt*nks+ks)*512 + lane*8 + j] = W[mt*16+(lane&15)][ks*32+(lane>>4)*8+j]
__global__ void k_pack_frag(const float* __restrict__ src, u16* __restrict__ dst,
                            int M, int K, int L, long src_lstride) {
  int nks = K >> 5;
  long per = (long)M * K;
  long total = per * L;
  for (long idx = blockIdx.x * (long)blockDim.x + threadIdx.x; idx < total; idx += (long)gridDim.x * blockDim.x) {
    int l = (int)(idx / per); long r = idx - (long)l * per;
    int j = (int)(r & 7); int lane = (int)((r >> 3) & 63); int fid = (int)(r >> 9);
    int ks = fid % nks; int mt = fid / nks;
    int row = mt * 16 + (lane & 15);
    int col = ks * 32 + ((lane >> 4) << 3) + j;
    dst[idx] = f2bf(src[l * src_lstride + (long)row * K + col]);
  }
}

// GAU fused weights: logical W[l][256][896]: k<384 tap0, k<768 tap1, else psig(lc chans 0..127)
__global__ void k_pack_frag_gau(const float* __restrict__ sig_w, const float* __restrict__ gate_w,
                                const float* __restrict__ psig_w, const float* __restrict__ pgate_w,
                                u16* __restrict__ dstF, u16* __restrict__ dstG) {
  const long per = 229376; // 16mt * 28ks * 512
  long total = per * 20;
  for (long idx = blockIdx.x * (long)blockDim.x + threadIdx.x; idx < total; idx += (long)gridDim.x * blockDim.x) {
    int l = (int)(idx / per); long r = idx - (long)l * per;
    int j = (int)(r & 7); int lane = (int)((r >> 3) & 63); int fid = (int)(r >> 9);
    int ks = fid % 28; int mt = fid / 28;
    int row = mt * 16 + (lane & 15);
    int k = ks * 32 + ((lane >> 4) << 3) + j;
    float vF, vG;
    if (k < 384) {
      vF = sig_w[(((long)l * 256 + row) * 384 + k) * 2 + 0];
      vG = gate_w[(((long)l * 256 + row) * 384 + k) * 2 + 0];
    } else if (k < 768) {
      vF = sig_w[(((long)l * 256 + row) * 384 + (k - 384)) * 2 + 1];
      vG = gate_w[(((long)l * 256 + row) * 384 + (k - 384)) * 2 + 1];
    } else {
      vF = psig_w[((long)l * 256 + row) * 256 + (k - 768)];
      vG = pgate_w[((long)l * 256 + row) * 256 + (k - 768)];
    }
    dstF[idx] = f2bf(vF);
    dstG[idx] = f2bf(vG);
  }
}

// tconv per-phase weight pack (f32, stages 1-3): dst[p][i*nk+m][o] = w[i][o][K-1-(S-1-p)-m*S]
__global__ void k_pack_tconv(const float* __restrict__ w, float* __restrict__ dst,
                             int S, int K, int nk) {
  int Ktot = 128 * nk;
  long total = (long)S * Ktot * 128;
  for (long idx = blockIdx.x * (long)blockDim.x + threadIdx.x; idx < total; idx += (long)gridDim.x * blockDim.x) {
    int o = (int)(idx & 127);
    long tmp = idx >> 7;
    int k = (int)(tmp % Ktot);
    int p = (int)(tmp / Ktot);
    int i = k / nk, m = k % nk;
    dst[idx] = w[((long)i * 128 + o) * K + (K - 1 - (S - 1 - p) - m * S)];
  }
}

// stage-4 tconv weights, fragment-packed per phase: M=128, K=512 (k = i*4+m), S=4, KW=16
__global__ void k_pack_tc4f(const float* __restrict__ w, u16* __restrict__ dst) {
  const long perp = 65536; // 8mt * 16ks * 512
  long total = perp * 4;
  for (long idx = blockIdx.x * (long)blockDim.x + threadIdx.x; idx < total; idx += (long)gridDim.x * blockDim.x) {
    int p = (int)(idx / perp); long r = idx - (long)p * perp;
    int j = (int)(r & 7); int lane = (int)((r >> 3) & 63); int fid = (int)(r >> 9);
    int ks = fid & 15; int mt = fid >> 4;
    int o = mt * 16 + (lane & 15);
    int k = ks * 32 + ((lane >> 4) << 3) + j;
    int i = k >> 2, m = k & 3;
    dst[idx] = f2bf(w[((long)i * 128 + o) * 16 + (12 + p - 4 * m)]);
  }
}

// im2col for stage-4 tconv input: dst[b][j][i*4+m] = lcs3[b][i][j+m]  (bf16)
__global__ void k_im2col3(const float* __restrict__ lcs3, u16* __restrict__ dst) {
  long total = 4L * 4580 * 512;
  for (long idx = blockIdx.x * (long)blockDim.x + threadIdx.x; idx < total; idx += (long)gridDim.x * blockDim.x) {
    int col = (int)(idx & 511);
    long t2 = idx >> 9;
    int jj = (int)(t2 % 4580);
    int b = (int)(t2 / 4580);
    int i = col >> 2, m = col & 3;
    float v = (jj + m < 4580) ? lcs3[((long)b * 128 + i) * 4580 + jj + m] : 0.0f;
    dst[idx] = f2bf(v);
  }
}

__global__ void k_gc(const float* __restrict__ emb_w, const float* __restrict__ emb_b,
                     const int* __restrict__ spk, float* __restrict__ gc) {
  int i = threadIdx.x + blockIdx.x * blockDim.x;
  if (i < 512) { int b = i / 128, g = i % 128; gc[b * 128 + g] = emb_w[g * 40 + spk[b]] + emb_b[g]; }
}

__global__ void k_cbias(const float* __restrict__ psig_w, const float* __restrict__ pgate_w,
                        const float* __restrict__ sig_b, const float* __restrict__ gate_b,
                        const float* __restrict__ gc, float* __restrict__ cbias) {
  int l = blockIdx.x; int fg = blockIdx.y >> 2; int b = blockIdx.y & 3; int c = threadIdx.x;
  const float* p = fg ? pgate_w : psig_w;
  const float* bb = fg ? gate_b : sig_b;
  float acc = bb[l * 256 + c];
  const float* prow = p + ((long)(l * 256 + c)) * 256 + 128;
  const float* g = gc + b * 128;
  for (int k = 0; k < 128; ++k) acc += prow[k] * g[k];
  cbias[((l * 2 + fg) * 4 + b) * 256 + c] = acc;
}

// jitter-gather + conv3 (VALID): out (B,128,62) f32 ch-major, stride 64
__global__ void k_lc0(const float* __restrict__ lc_sparse, const int* __restrict__ jit,
                      const float* __restrict__ w, const float* __restrict__ bias, float* __restrict__ out) {
  int b = blockIdx.x; int t = blockIdx.y; int co = threadIdx.x; // 128
  __shared__ float xs[64][3];
  for (int i = threadIdx.x; i < 192; i += blockDim.x) {
    int ci = i / 3, kk = i % 3;
    xs[ci][kk] = lc_sparse[((long)b * 64 + ci) * 64 + jit[b * 64 + t + kk]];
  }
  __syncthreads();
  float acc = bias[co];
  #pragma unroll 8
  for (int ci = 0; ci < 64; ++ci) {
    const float* wr = w + ((long)co * 64 + ci) * 3;
    acc += wr[0] * xs[ci][0] + wr[1] * xs[ci][1] + wr[2] * xs[ci][2];
  }
  out[((long)b * 128 + co) * 64 + t] = acc;
}

// Transposed conv stages 1-3 (f32 tiled GEMM, small) — out f32 ch-major
template<int NK>
__global__ __launch_bounds__(256) void k_tconvg(
    const float* __restrict__ xin, int Lin, int xstride,
    float* __restrict__ yout, int Lout, int ostride,
    const float* __restrict__ wp, const float* __restrict__ bias, int S) {
  const int Ktot = 128 * NK;
  __shared__ __align__(16) float Ws[32][64];
  __shared__ __align__(16) float Xs[32][64];
  int b = blockIdx.z;
  int p = blockIdx.y >> 1, bm0 = (blockIdx.y & 1) * 64;
  int j0 = blockIdx.x * 64;
  int tid = threadIdx.x, tn = tid & 15, tm = tid >> 4;
  float acc[4][4] = {};
  int kchunks = Ktot / 32;
  for (int kc = 0; kc < kchunks; ++kc) {
    int k0 = kc * 32;
    {
      int kk = tid >> 3, m8 = (tid & 7) * 8;
      const float* src = wp + ((long)p * Ktot + k0 + kk) * 128 + bm0 + m8;
      float4 f1 = *(const float4*)src;
      float4 f2 = *(const float4*)(src + 4);
      Ws[kk][m8 + 0] = f1.x; Ws[kk][m8 + 1] = f1.y; Ws[kk][m8 + 2] = f1.z; Ws[kk][m8 + 3] = f1.w;
      Ws[kk][m8 + 4] = f2.x; Ws[kk][m8 + 5] = f2.y; Ws[kk][m8 + 6] = f2.z; Ws[kk][m8 + 7] = f2.w;
    }
    #pragma unroll
    for (int rr = 0; rr < 8; ++rr) {
      int kk = rr * 4 + (tid >> 6), tt = tid & 63;
      int k = k0 + kk;
      int i = k / NK, m = k % NK;
      int j = j0 + tt;
      Xs[kk][tt] = (j + m < Lin) ? xin[((long)(b * 128 + i)) * xstride + j + m] : 0.0f;
    }
    __syncthreads();
    #pragma unroll 8
    for (int kk = 0; kk < 32; ++kk) {
      float av[4], bv[4];
      #pragma unroll
      for (int i = 0; i < 4; ++i) av[i] = Ws[kk][tm * 4 + i];
      #pragma unroll
      for (int j = 0; j < 4; ++j) bv[j] = Xs[kk][tn * 4 + j];
      #pragma unroll
      for (int i = 0; i < 4; ++i)
        #pragma unroll
        for (int j = 0; j < 4; ++j) acc[i][j] = fmaf(av[i], bv[j], acc[i][j]);
    }
    __syncthreads();
  }
  #pragma unroll
  for (int jj = 0; jj < 4; ++jj) {
    int j = j0 + tn * 4 + jj;
    int t = j * S + p;
    if (t >= Lout) continue;
    #pragma unroll
    for (int i = 0; i < 4; ++i) {
      int o = bm0 + tm * 4 + i;
      yout[((long)b * 128 + o) * ostride + t] = acc[i][jj] + bias[o];
    }
  }
}

// stage-4 tconv via MFMA: B = im2col [b][j][512], per-phase packed W, out lcbf [b][t=4j+p][128]
__global__ __launch_bounds__(256) void k_tconv4m(
    const u16* __restrict__ im, const u16* __restrict__ Wp4,
    const float* __restrict__ bias, u16* __restrict__ out) {
  int lane = threadIdx.x & 63, wave = threadIdx.x >> 6;
  int b = blockIdx.z;
  int p = blockIdx.y >> 1, chb = (blockIdx.y & 1) << 6;
  int tbase = (blockIdx.x << 8) + (wave << 6);
  int lrow = lane & 15, lk = (lane >> 4) << 3;
  int mt0 = chb >> 4;
  const u16* Wp = Wp4 + (long)p * 65536;
  f32x4 zed = {0.f, 0.f, 0.f, 0.f};
  f32x4 acc[4][4];
  #pragma unroll
  for (int m = 0; m < 4; ++m)
    #pragma unroll
    for (int n = 0; n < 4; ++n) acc[m][n] = zed;
  const u16* ib = im + (long)b * 4580 * 512;
  for (int ks = 0; ks < 16; ++ks) {
    short8_t a[4];
    #pragma unroll
    for (int m = 0; m < 4; ++m)
      a[m] = *(const short8_t*)(Wp + ((long)((mt0 + m) * 16 + ks) << 9) + (lane << 3));
    #pragma unroll
    for (int n = 0; n < 4; ++n) {
      int j = tbase + (n << 4) + lrow;
      j = min(j, 4579);
      short8_t bv = *(const short8_t*)(ib + (long)j * 512 + (ks << 5) + lk);
      #pragma unroll
      for (int m = 0; m < 4; ++m)
        acc[m][n] = __builtin_amdgcn_mfma_f32_16x16x32_bf16(a[m], bv, acc[m][n], 0, 0, 0);
    }
  }
  #pragma unroll
  for (int n = 0; n < 4; ++n) {
    int j = tbase + (n << 4) + lrow;
    int t = j * 4 + p;
    if (t >= T_IN) continue;
    #pragma unroll
    for (int m = 0; m < 4; ++m) {
      int ch0 = chb + (m << 4) + ((lane >> 4) << 2);
      f32x4 bb = *(const f32x4*)(bias + ch0);
      ushort4 o;
      o.x = f2bf(acc[m][n][0] + bb[0]);
      o.y = f2bf(acc[m][n][1] + bb[1]);
      o.z = f2bf(acc[m][n][2] + bb[2]);
      o.w = f2bf(acc[m][n][3] + bb[3]);
      *(ushort4*)(out + ((long)b * T_IN + t) * 128 + ch0) = o;
    }
  }
}

// wav transpose: f32 ch-major [b][256][T] -> bf16 t-major [b][T][256]
__global__ __launch_bounds__(256) void k_wav_t(const float* __restrict__ wav, u16* __restrict__ dst) {
  __shared__ float xs[32][65];
  int b = blockIdx.z, c0 = blockIdx.y * 32, t0 = blockIdx.x * 64;
  int tid = threadIdx.x;
  #pragma unroll
  for (int i = 0; i < 8; ++i) {
    int idx = tid + i * 256;
    int c = idx >> 6, tl = idx & 63;
    int t = t0 + tl; if (t >= T_IN) t = T_IN - 1;
    xs[c][tl] = wav[((long)b * 256 + c0 + c) * T_IN + t];
  }
  __syncthreads();
  #pragma unroll
  for (int i = 0; i < 8; ++i) {
    int idx = tid + i * 256;
    int tl = idx >> 5, c = idx & 31;
    int t = t0 + tl;
    if (t < T_IN) dst[((long)b * T_IN + t) * 256 + c0 + c] = f2bf(xs[c][tl]);
  }
}

// base 1x1 conv MFMA: M=384, K=256, B = wavT, out xA bf16 t-major [b][t][384]
__global__ __launch_bounds__(256) void k_basem(
    const u16* __restrict__ wavT, const u16* __restrict__ Wp,
    const float* __restrict__ bias, u16* __restrict__ X) {
  int lane = threadIdx.x & 63, wave = threadIdx.x >> 6;
  int b = blockIdx.z, chb = blockIdx.y << 6;
  int tbase = (blockIdx.x << 8) + (wave << 6);
  int lrow = lane & 15, lk = (lane >> 4) << 3;
  int mt0 = chb >> 4;
  f32x4 zed = {0.f, 0.f, 0.f, 0.f};
  f32x4 acc[4][4];
  #pragma unroll
  for (int m = 0; m < 4; ++m)
    #pragma unroll
    for (int n = 0; n < 4; ++n) acc[m][n] = zed;
  const u16* xb = wavT + (long)b * T_IN * 256;
  for (int ks = 0; ks < 8; ++ks) {
    short8_t a[4];
    #pragma unroll
    for (int m = 0; m < 4; ++m)
      a[m] = *(const short8_t*)(Wp + ((long)((mt0 + m) * 8 + ks) << 9) + (lane << 3));
    #pragma unroll
    for (int n = 0; n < 4; ++n) {
      int row = tbase + (n << 4) + lrow;
      row = min(row, T_IN - 1);
      short8_t bv = *(const short8_t*)(xb + (long)row * 256 + (ks << 5) + lk);
      #pragma unroll
      for (int m = 0; m < 4; ++m)
        acc[m][n] = __builtin_amdgcn_mfma_f32_16x16x32_bf16(a[m], bv, acc[m][n], 0, 0, 0);
    }
  }
  #pragma unroll
  for (int n = 0; n < 4; ++n) {
    int t = tbase + (n << 4) + lrow;
    if (t >= T_IN) continue;
    #pragma unroll
    for (int m = 0; m < 4; ++m) {
      int ch0 = chb + (m << 4) + ((lane >> 4) << 2);
      f32x4 bb = *(const f32x4*)(bias + ch0);
      ushort4 o;
      o.x = f2bf(acc[m][n][0] + bb[0]);
      o.y = f2bf(acc[m][n][1] + bb[1]);
      o.z = f2bf(acc[m][n][2] + bb[2]);
      o.w = f2bf(acc[m][n][3] + bb[3]);
      *(ushort4*)(X + ((long)b * T_IN + t) * 384 + ch0) = o;
    }
  }
}

// ---- Fused layer kernel ----
// Block: 512 thr (8 waves), 64 t-positions, full layer.
// Phase 1 (GAU K=896): wave w owns 32 ch [w*32,w*32+32); B staged to LDS in
// fragment order (dbuf 2x4KB, reg-staged issue-early/write-late, 1 barrier/ks).
// Activation -> z into 32KB LDS tile [64t][256ch], XOR swizzle byte^=(t&7)<<4.
// Phase 2: 40 16-ch tiles (0-15 skip M=256, 16-39 res M=384), 5 per wave,
// K=256 from z LDS. Skip: f32 RMW at t-sl. Res: +residual -> Xout.
__global__ __launch_bounds__(512) void k_layer(
    const u16* __restrict__ Xc, const u16* __restrict__ Lc,
    const u16* __restrict__ WpF, const u16* __restrict__ WpG,
    const u16* __restrict__ Wskp, const u16* __restrict__ Wres,
    const float* __restrict__ cb, float* __restrict__ skip,
    u16* __restrict__ Xout,
    int Lz, int Lx, int d, int cl, int sl, int lw, int first, int ntiles) {
  __shared__ __align__(16) u16 zt[64 * 256];   // 32KB z tile
  __shared__ __align__(16) u16 stg[2][2048];   // 2x4KB B staging
  int tid = threadIdx.x, lane = tid & 63, wave = tid >> 6;
  int b = blockIdx.z;
  // bijective XCD swizzle (m204) on t-block index
  int nt = gridDim.x, bo = blockIdx.x;
  int q8 = nt >> 3, r8 = nt & 7, x8 = bo & 7, i8 = bo >> 3;
  int tb = (x8 < r8 ? x8 * (q8 + 1) : r8 * (q8 + 1) + (x8 - r8) * q8) + i8;
  int tbase = tb << 6;
  int lrow = lane & 15, lk16 = lane >> 4;
  const u16* xb = Xc + (long)b * T_IN * 384;
  const u16* lb = Lc + (long)b * T_IN * 128;

  // staging source (waves 0-3 stage frag n=wave): 16B per lane
  auto srcp = [&](int ks) -> const u16* {
    const u16* s; int koff, rowadd, ldB, clampv;
    if (ks < 12)      { s = xb; koff = ks * 32;       rowadd = 0;  ldB = 384; clampv = Lx - 1; }
    else if (ks < 24) { s = xb; koff = ks * 32 - 384; rowadd = d;  ldB = 384; clampv = Lx - 1; }
    else              { s = lb; koff = ks * 32 - 768; rowadd = cl; ldB = 128; clampv = T_IN - 1; }
    int row = tbase + (wave << 4) + lrow + rowadd;
    row = min(row, clampv);
    return s + (long)row * ldB + koff + (lk16 << 3);
  };

  f32x4 zed = {0.f, 0.f, 0.f, 0.f};
  f32x4 accF[2][4], accG[2][4];
  #pragma unroll
  for (int m = 0; m < 2; ++m)
    #pragma unroll
    for (int n = 0; n < 4; ++n) { accF[m][n] = zed; accG[m][n] = zed; }
  int mt0 = wave << 1;

  if (wave < 4) {
    short8_t v = *(const short8_t*)srcp(0);
    *(short8_t*)&stg[0][(wave << 9) + (lane << 3)] = v;
  }
  __syncthreads();
  int cur = 0;
  for (int ks = 0; ks < 28; ++ks) {
    short8_t nv;
    bool st = (wave < 4) && (ks < 27);
    if (st) nv = *(const short8_t*)srcp(ks + 1);   // issue early
    short8_t af[2], ag[2];
    #pragma unroll
    for (int m = 0; m < 2; ++m) {
      long fo = ((long)((mt0 + m) * 28 + ks) << 9) + (lane << 3);
      af[m] = *(const short8_t*)(WpF + fo);
      ag[m] = *(const short8_t*)(WpG + fo);
    }
    #pragma unroll
    for (int n = 0; n < 4; ++n) {
      short8_t bv = *(const short8_t*)&stg[cur][(n << 9) + (lane << 3)];
      #pragma unroll
      for (int m = 0; m < 2; ++m) {
        accF[m][n] = __builtin_amdgcn_mfma_f32_16x16x32_bf16(af[m], bv, accF[m][n], 0, 0, 0);
        accG[m][n] = __builtin_amdgcn_mfma_f32_16x16x32_bf16(ag[m], bv, accG[m][n], 0, 0, 0);
      }
    }
    if (st) *(short8_t*)&stg[cur ^ 1][(wave << 9) + (lane << 3)] = nv;  // write late
    __syncthreads();
    cur ^= 1;
  }

  // activation -> z LDS (swizzled)
  const float* cbF = cb + b * 256;
  const float* cbG = cb + 1024 + b * 256;
  #pragma unroll
  for (int m = 0; m < 2; ++m) {
    int ch0 = (wave << 5) + (m << 4) + (lk16 << 2);
    f32x4 bf = *(const f32x4*)(cbF + ch0);
    f32x4 bg = *(const f32x4*)(cbG + ch0);
    #pragma unroll
    for (int n = 0; n < 4; ++n) {
      ushort4 o;
      #pragma unroll
      for (int r = 0; r < 4; ++r) {
        float f = accF[m][n][r] + bf[r];
        float g = accG[m][n][r] + bg[r];
        f = fminf(fmaxf(f, -15.f), 15.f);
        float e2 = __expf(2.f * f);
        float th = 1.f - 2.f * __builtin_amdgcn_rcpf(e2 + 1.f);
        float sg = __builtin_amdgcn_rcpf(1.f + __expf(-g));
        u16 zz = f2bf(th * sg);
        if (r == 0) o.x = zz; else if (r == 1) o.y = zz; else if (r == 2) o.z = zz; else o.w = zz;
      }
      int tl = (n << 4) + lrow;
      int bofs = ((tl << 9) + (ch0 << 1)) ^ ((tl & 7) << 4);
      *(ushort4*)((char*)zt + bofs) = o;
    }
  }
  __syncthreads();

  // phase 2
  int ntpw = ntiles >> 3;
  for (int qt = 0; qt < ntpw; ++qt) {
    int tau = wave * ntpw + qt;
    bool issk = tau < 16;
    int mt = issk ? tau : tau - 16;
    const u16* Wp = issk ? Wskp : Wres;
    f32x4 acc[4];
    #pragma unroll
    for (int n = 0; n < 4; ++n) acc[n] = zed;
    for (int ks = 0; ks < 8; ++ks) {
      short8_t a = *(const short8_t*)(Wp + ((long)((mt << 3) + ks) << 9) + (lane << 3));
      #pragma unroll
      for (int n = 0; n < 4; ++n) {
        int tl = (n << 4) + lrow;
        int bofs = ((tl << 9) + (ks << 6) + (lk16 << 4)) ^ ((tl & 7) << 4);
        short8_t bv = *(const short8_t*)((char*)zt + bofs);
        acc[n] = __builtin_amdgcn_mfma_f32_16x16x32_bf16(a, bv, acc[n], 0, 0, 0);
      }
    }
    int ch0 = (mt << 4) + (lk16 << 2);
    #pragma unroll
    for (int n = 0; n < 4; ++n) {
      int tg = tbase + (n << 4) + lrow;
      if (issk) {
        if (tg >= sl && tg < Lz) {
          float* p = skip + ((long)b * T_OUT + (tg - sl)) * 256 + ch0;
          if (first) { *(f32x4*)p = acc[n]; }
          else { f32x4 v = *(f32x4*)p; v += acc[n]; *(f32x4*)p = v; }
        }
      } else if (tg < Lz) {
        const u16* rp = Xc + ((long)b * T_IN + tg + lw) * 384 + ch0;
        ushort4 rv = *(const ushort4*)rp;
        ushort4 o;
        o.x = f2bf(acc[n][0] + bf2f(rv.x));
        o.y = f2bf(acc[n][1] + bf2f(rv.y));
        o.z = f2bf(acc[n][2] + bf2f(rv.z));
        o.w = f2bf(acc[n][3] + bf2f(rv.w));
        *(ushort4*)(Xout + ((long)b * T_IN + tg) * 384 + ch0) = o;
      }
    }
  }
}

// post1: h1 = relu(W1 @ relu(skip) + b1), M=512, K=256; B from f32 skip with inline relu+cvt
__global__ __launch_bounds__(256) void k_post1(
    const float* __restrict__ skip, const u16* __restrict__ Wp,
    const float* __restrict__ b1, u16* __restrict__ h1) {
  int lane = threadIdx.x & 63, wave = threadIdx.x >> 6;
  int b = blockIdx.z, qb = blockIdx.y << 6;
  int tbase = (blockIdx.x << 8) + (wave << 6);
  int lrow = lane & 15, lk = (lane >> 4) << 3;
  int mt0 = qb >> 4;
  f32x4 zed = {0.f, 0.f, 0.f, 0.f};
  f32x4 acc[4][4];
  #pragma unroll
  for (int m = 0; m < 4; ++m)
    #pragma unroll
    for (int n = 0; n < 4; ++n) acc[m][n] = zed;
  const float* sb = skip + (long)b * T_OUT * 256;
  for (int ks = 0; ks < 8; ++ks) {
    short8_t a[4];
    #pragma unroll
    for (int m = 0; m < 4; ++m)
      a[m] = *(const short8_t*)(Wp + ((long)((mt0 + m) * 8 + ks) << 9) + (lane << 3));
    #pragma unroll
    for (int n = 0; n < 4; ++n) {
      int row = tbase + (n << 4) + lrow;
      row = min(row, T_OUT - 1);
      const float* src = sb + (long)row * 256 + (ks << 5) + lk;
      f32x4 v0 = *(const f32x4*)src;
      f32x4 v1 = *(const f32x4*)(src + 4);
      short8_t bv;
      #pragma unroll
      for (int j = 0; j < 4; ++j) bv[j] = (short)f2bf(fmaxf(v0[j], 0.f));
      #pragma unroll
      for (int j = 0; j < 4; ++j) bv[4 + j] = (short)f2bf(fmaxf(v1[j], 0.f));
      #pragma unroll
      for (int m = 0; m < 4; ++m)
        acc[m][n] = __builtin_amdgcn_mfma_f32_16x16x32_bf16(a[m], bv, acc[m][n], 0, 0, 0);
    }
  }
  #pragma unroll
  for (int n = 0; n < 4; ++n) {
    int t = tbase + (n << 4) + lrow;
    if (t >= T_OUT) continue;
    #pragma unroll
    for (int m = 0; m < 4; ++m) {
      int ch0 = qb + (m << 4) + ((lane >> 4) << 2);
      f32x4 bb = *(const f32x4*)(b1 + ch0);
      ushort4 o;
      o.x = f2bf(fmaxf(acc[m][n][0] + bb[0], 0.f));
      o.y = f2bf(fmaxf(acc[m][n][1] + bb[1], 0.f));
      o.z = f2bf(fmaxf(acc[m][n][2] + bb[2], 0.f));
      o.w = f2bf(fmaxf(acc[m][n][3] + bb[3], 0.f));
      *(ushort4*)(h1 + ((long)b * T_OUT + t) * 512 + ch0) = o;
    }
  }
}

// post2 + log_softmax: M=256 (4 waves x 64q), K=512, out f32 [b][q][T_OUT]
__global__ __launch_bounds__(256) void k_post2sm(
    const u16* __restrict__ h1, const u16* __restrict__ Wp,
    const float* __restrict__ b2, float* __restrict__ out) {
  __shared__ float redM[4][64];
  __shared__ float redS[4][64];
  int lane = threadIdx.x & 63, wave = threadIdx.x >> 6;
  int b = blockIdx.z;
  int qb = wave << 6;
  int tb = blockIdx.x << 6;
  int lrow = lane & 15, lk = (lane >> 4) << 3;
  int mt0 = qb >> 4;
  f32x4 zed = {0.f, 0.f, 0.f, 0.f};
  f32x4 acc[4][4];
  #pragma unroll
  for (int m = 0; m < 4; ++m)
    #pragma unroll
    for (int n = 0; n < 4; ++n) acc[m][n] = zed;
  const u16* hb = h1 + (long)b * T_OUT * 512;
  for (int ks = 0; ks < 16; ++ks) {
    short8_t a[4];
    #pragma unroll
    for (int m = 0; m < 4; ++m)
      a[m] = *(const short8_t*)(Wp + ((long)((mt0 + m) * 16 + ks) << 9) + (lane << 3));
    #pragma unroll
    for (int n = 0; n < 4; ++n) {
      int row = tb + (n << 4) + lrow;
      row = min(row, T_OUT - 1);
      short8_t bv = *(const short8_t*)(hb + (long)row * 512 + (ks << 5) + lk);
      #pragma unroll
      for (int m = 0; m < 4; ++m)
        acc[m][n] = __builtin_amdgcn_mfma_f32_16x16x32_bf16(a[m], bv, acc[m][n], 0, 0, 0);
    }
  }
  #pragma unroll
  for (int m = 0; m < 4; ++m) {
    int q0 = qb + (m << 4) + ((lane >> 4) << 2);
    f32x4 bb = *(const f32x4*)(b2 + q0);
    #pragma unroll
    for (int n = 0; n < 4; ++n) acc[m][n] += bb;
  }
  float fm[4], fs[4];
  #pragma unroll
  for (int n = 0; n < 4; ++n) {
    float pm = -1e30f;
    #pragma unroll
    for (int m = 0; m < 4; ++m)
      #pragma unroll
      for (int r = 0; r < 4; ++r) pm = fmaxf(pm, acc[m][n][r]);
    pm = fmaxf(pm, __shfl_xor(pm, 16));
    pm = fmaxf(pm, __shfl_xor(pm, 32));
    if (lane < 16) redM[wave][(n << 4) + lane] = pm;
  }
  __syncthreads();
  #pragma unroll
  for (int n = 0; n < 4; ++n) {
    float mm = redM[0][(n << 4) + lrow];
    mm = fmaxf(mm, redM[1][(n << 4) + lrow]);
    mm = fmaxf(mm, redM[2][(n << 4) + lrow]);
    mm = fmaxf(mm, redM[3][(n << 4) + lrow]);
    fm[n] = mm;
    float ps = 0.f;
    #pragma unroll
    for (int m = 0; m < 4; ++m)
      #pragma unroll
      for (int r = 0; r < 4; ++r) ps += __expf(acc[m][n][r] - mm);
    ps += __shfl_xor(ps, 16);
    ps += __shfl_xor(ps, 32);
    if (lane < 16) redS[wave][(n << 4) + lane] = ps;
  }
  __syncthreads();
  #pragma unroll
  for (int n = 0; n < 4; ++n) {
    float ss = redS[0][(n << 4) + lrow] + redS[1][(n << 4) + lrow] +
               redS[2][(n << 4) + lrow] + redS[3][(n << 4) + lrow];
    fs[n] = fm[n] + logf(ss);
  }
  #pragma unroll
  for (int n = 0; n < 4; ++n) {
    int t = tb + (n << 4) + lrow;
    if (t >= T_OUT) continue;
    #pragma unroll
    for (int m = 0; m < 4; ++m) {
      int q0 = qb + (m << 4) + ((lane >> 4) << 2);
      #pragma unroll
      for (int r = 0; r < 4; ++r)
        out[((long)b * 256 + q0 + r) * T_OUT + t] = acc[m][n][r] - fs[n];
    }
  }
}

extern "C" void kernel_launch(void* const* d_in, const int* in_sizes, int n_in,
                              void* d_out, int out_size, void* d_ws, size_t ws_size,
                              hipStream_t stream) {
  const float* wav       = (const float*)d_in[0];
  const float* lc_sparse = (const float*)d_in[1];
  const float* lc_conv_w = (const float*)d_in[2];
  const float* lc_conv_b = (const float*)d_in[3];
  const float* ups_w[4]  = {(const float*)d_in[4], (const float*)d_in[6], (const float*)d_in[8], (const float*)d_in[10]};
  const float* ups_b[4]  = {(const float*)d_in[5], (const float*)d_in[7], (const float*)d_in[9], (const float*)d_in[11]};
  const float* emb_w     = (const float*)d_in[12];
  const float* emb_b     = (const float*)d_in[13];
  const float* base_w    = (const float*)d_in[14];
  const float* base_b    = (const float*)d_in[15];
  const float* sig_w     = (const float*)d_in[16];
  const float* sig_b     = (const float*)d_in[17];
  const float* gate_w    = (const float*)d_in[18];
  const float* gate_b    = (const float*)d_in[19];
  const float* psig_w    = (const float*)d_in[20];
  const float* pgate_w   = (const float*)d_in[21];
  const float* skp_w     = (const float*)d_in[22];
  const float* res_w     = (const float*)d_in[23];
  const float* post1_w   = (const float*)d_in[24];
  const float* post1_b   = (const float*)d_in[25];
  const float* post2_w   = (const float*)d_in[26];
  const float* post2_b   = (const float*)d_in[27];
  const int* spk         = (const int*)d_in[28];
  const int* jit         = (const int*)d_in[29];
  float* out = (float*)d_out;

  size_t off = 0;
  auto alloc = [&](size_t bytes) -> void* {
    off = (off + 255) & ~(size_t)255;
    void* p = (char*)d_ws + off;
    off += bytes;
    return p;
  };
  u16* wfgF   = (u16*)alloc(20L * 229376 * 2);
  u16* wfgG   = (u16*)alloc(20L * 229376 * 2);
  u16* wskpF  = (u16*)alloc(20L * 65536 * 2);
  u16* wresF  = (u16*)alloc(20L * 98304 * 2);
  u16* wbaseF = (u16*)alloc(384L * 256 * 2);
  u16* wp1F   = (u16*)alloc(512L * 256 * 2);
  u16* wp2F   = (u16*)alloc(256L * 512 * 2);
  float* wtc1 = (float*)alloc(5L * 640 * 128 * 4);
  float* wtc2 = (float*)alloc(4L * 512 * 128 * 4);
  float* wtc3 = (float*)alloc(4L * 512 * 128 * 4);
  u16* wtc4F  = (u16*)alloc(4L * 65536 * 2);
  float* cbias = (float*)alloc(20L * 2 * 4 * 256 * 4);
  float* gc    = (float*)alloc(4L * 128 * 4);
  u16* lcbf    = (u16*)alloc(4L * T_IN * 128 * 2);
  u16* xA      = (u16*)alloc(4L * T_IN * 384 * 2);
  u16* xB      = (u16*)alloc(4L * T_IN * 384 * 2);
  u16* zbuf    = (u16*)alloc(4L * T_IN * 256 * 2);   // scratch (lc chain aliases)
  float* skip  = (float*)alloc(4L * T_OUT * 256 * 4);
  // temporal aliases (stream-ordered, lifetimes disjoint):
  float* lcs0 = (float*)zbuf;
  float* lcs1 = lcs0 + 4L * 128 * 64;
  float* lcs2 = lcs1 + 4L * 128 * 290;
  float* lcs3 = lcs2 + 4L * 128 * 1148;
  u16* im3    = xB;
  u16* wavT   = (u16*)skip;
  u16* h1bf   = xA;
  (void)ws_size; (void)in_sizes; (void)n_in; (void)out_size;

  // weight packs
  k_pack_frag_gau<<<4480, 256, 0, stream>>>(sig_w, gate_w, psig_w, pgate_w, wfgF, wfgG);
  k_pack_frag<<<1280, 256, 0, stream>>>(skp_w, wskpF, 256, 256, 20, 256L * 256);
  k_pack_frag<<<1920, 256, 0, stream>>>(res_w, wresF, 384, 256, 20, 384L * 256);
  k_pack_frag<<<96, 256, 0, stream>>>(base_w, wbaseF, 384, 256, 1, 0);
  k_pack_frag<<<128, 256, 0, stream>>>(post1_w, wp1F, 512, 256, 1, 0);
  k_pack_frag<<<128, 256, 0, stream>>>(post2_w, wp2F, 256, 512, 1, 0);
  k_pack_tconv<<<320, 256, 0, stream>>>(ups_w[0], wtc1, 5, 25, 5);
  k_pack_tconv<<<256, 256, 0, stream>>>(ups_w[1], wtc2, 4, 16, 4);
  k_pack_tconv<<<256, 256, 0, stream>>>(ups_w[2], wtc3, 4, 16, 4);
  k_pack_tc4f<<<256, 256, 0, stream>>>(ups_w[3], wtc4F);
  k_gc<<<1, 512, 0, stream>>>(emb_w, emb_b, spk, gc);
  k_cbias<<<dim3(20, 8), 256, 0, stream>>>(psig_w, pgate_w, sig_b, gate_b, gc, cbias);

  // local-conditioning chain
  k_lc0<<<dim3(4, 62), 128, 0, stream>>>(lc_sparse, jit, lc_conv_w, lc_conv_b, lcs0);
  k_tconvg<5><<<dim3(1, 10, 4), 256, 0, stream>>>(lcs0, 62, 64, lcs1, 290, 290, wtc1, ups_b[0], 5);
  k_tconvg<4><<<dim3(5, 8, 4), 256, 0, stream>>>(lcs1, 290, 290, lcs2, 1148, 1148, wtc2, ups_b[1], 4);
  k_tconvg<4><<<dim3(18, 8, 4), 256, 0, stream>>>(lcs2, 1148, 1148, lcs3, 4580, 4580, wtc3, ups_b[2], 4);
  k_im2col3<<<2048, 256, 0, stream>>>(lcs3, im3);
  k_tconv4m<<<dim3(18, 8, 4), 256, 0, stream>>>(im3, wtc4F, ups_b[3], lcbf);

  // wav transpose + base 1x1 conv (MFMA) -> xA t-major bf16
  k_wav_t<<<dim3(287, 8, 4), 256, 0, stream>>>(wav, wavT);
  k_basem<<<dim3(72, 6, 4), 256, 0, stream>>>(wavT, wbaseF, base_b, xA);

  static const int DILS[20] = {1, 2, 4, 8, 16, 32, 64, 128, 256, 512,
                               1, 2, 4, 8, 16, 32, 64, 128, 256, 512};
  int cum = 0;
  u16* xc = xA; u16* xn = xB;
  for (int l = 0; l < 20; ++l) {
    int dd = DILS[l], lw = dd, cl = cum + lw;
    int Lx = T_IN - cum, Lz = T_IN - cl;
    int sl = 2046 - cl;
    int nt = (Lz + 63) / 64;
    int ntiles = (l == 19) ? 16 : 40;
    k_layer<<<dim3(nt, 1, 4), 512, 0, stream>>>(
        xc, lcbf, wfgF + (long)l * 229376, wfgG + (long)l * 229376,
        wskpF + (long)l * 65536, wresF + (long)l * 98304,
        cbias + (long)l * 2048, skip, xn,
        Lz, Lx, dd, cl, sl, lw, (l == 0) ? 1 : 0, ntiles);
    cum = cl;
    u16* t = xc; xc = xn; xn = t;
  }

  k_post1<<<dim3(64, 8, 4), 256, 0, stream>>>(skip, wp1F, post1_b, h1bf);
  k_post2sm<<<dim3(255, 1, 4), 256, 0, stream>>>(h1bf, wp2F, post2_b, out);
}